// Round 13
// baseline (1151.953 us; speedup 1.0000x reference)
//
#include <hip/hip_runtime.h>
#include <hip/hip_bf16.h>
#include <math.h>

typedef __bf16 bf16;
typedef __bf16 bf16x4 __attribute__((ext_vector_type(4)));
typedef __bf16 bf16x8 __attribute__((ext_vector_type(8)));
typedef float  f32x4  __attribute__((ext_vector_type(4)));

typedef __attribute__((address_space(1))) void gvoid_t;
typedef __attribute__((address_space(3))) void lvoid_t;

static __device__ __forceinline__ void gload16(const void* g, void* l) {
  // async global->LDS, 16B per lane; LDS dest wave-uniform base (HW adds lane*16)
  __builtin_amdgcn_global_load_lds((gvoid_t*)g, (lvoid_t*)l, 16, 0, 0);
}

static __device__ __forceinline__ float fexp2(float x) {
  return __builtin_amdgcn_exp2f(x);   // v_exp_f32: 2^x
}

static __device__ __forceinline__ unsigned pack2bf(float lo, float hi) {
  unsigned short l = __builtin_bit_cast(unsigned short, (bf16)lo);
  unsigned short h = __builtin_bit_cast(unsigned short, (bf16)hi);
  return ((unsigned)h << 16) | (unsigned)l;
}

// ---------------------------------------------------------------- converts
__global__ __launch_bounds__(256) void cvt_bf16(const float* __restrict__ in,
                                                bf16* __restrict__ out, int n8) {
  int i = blockIdx.x * 256 + threadIdx.x;
  if (i >= n8) return;
  const float4* p = (const float4*)(in + (size_t)i * 8);
  float4 v0 = p[0], v1 = p[1];
  bf16x8 o;
  o[0] = (bf16)v0.x; o[1] = (bf16)v0.y; o[2] = (bf16)v0.z; o[3] = (bf16)v0.w;
  o[4] = (bf16)v1.x; o[5] = (bf16)v1.y; o[6] = (bf16)v1.z; o[7] = (bf16)v1.w;
  *(bf16x8*)(out + (size_t)i * 8) = o;
}

// W [K][N] fp32 -> Wt [N][K] bf16 (32x32 LDS tiles)
__global__ __launch_bounds__(256) void tcvt(const float* __restrict__ W,
                                            bf16* __restrict__ Wt, int K, int N) {
  __shared__ float t[32][33];
  const int tid = threadIdx.x;
  const int r = tid >> 3, c4 = (tid & 7) * 4;
  const size_t grow = (size_t)(blockIdx.y * 32 + r);
  float4 v = *(const float4*)(W + grow * N + blockIdx.x * 32 + c4);
  t[r][c4 + 0] = v.x; t[r][c4 + 1] = v.y; t[r][c4 + 2] = v.z; t[r][c4 + 3] = v.w;
  __syncthreads();
  bf16x4 o = { (bf16)t[c4 + 0][r], (bf16)t[c4 + 1][r], (bf16)t[c4 + 2][r], (bf16)t[c4 + 3][r] };
  *(bf16x4*)(Wt + (size_t)(blockIdx.x * 32 + r) * K + blockIdx.y * 32 + c4) = o;
}

// ---------------------------------------------------------------- GEMM (NT, small shapes)
template <typename OutT>
__global__ __launch_bounds__(256) void gemm_bt(const bf16* __restrict__ A,
                                               const bf16* __restrict__ Bt,
                                               OutT* __restrict__ C,
                                               int N, int K) {
  __shared__ bf16 As[128 * 64];
  __shared__ bf16 Bs[128 * 64];
  const int tid = threadIdx.x;
  const int wid = tid >> 6, lane = tid & 63;
  const int g = lane >> 4, c = lane & 15;
  const int brow = blockIdx.y * 128, bcol = blockIdx.x * 128;
  const int wr = (wid >> 1) * 64, wc = (wid & 1) * 64;
  f32x4 acc[4][4] = {};

  for (int k0 = 0; k0 < K; k0 += 64) {
#pragma unroll
    for (int i = 0; i < 4; ++i) {
      const int off = i * 4096 + tid * 16;
      const int row = off >> 7, colb = off & 127;
      gload16((const char*)A + ((size_t)(brow + row) * K + k0) * 2 + colb,
              (char*)As + i * 4096 + wid * 1024);
      gload16((const char*)Bt + ((size_t)(bcol + row) * K + k0) * 2 + colb,
              (char*)Bs + i * 4096 + wid * 1024);
    }
    __syncthreads();
#pragma unroll
    for (int ks = 0; ks < 2; ++ks) {
      bf16x8 af[4], bfr[4];
#pragma unroll
      for (int t = 0; t < 4; ++t) {
        af[t]  = *(const bf16x8*)(As + (wr + t * 16 + c) * 64 + ks * 32 + g * 8);
        bfr[t] = *(const bf16x8*)(Bs + (wc + t * 16 + c) * 64 + ks * 32 + g * 8);
      }
#pragma unroll
      for (int mt = 0; mt < 4; ++mt)
#pragma unroll
        for (int nt = 0; nt < 4; ++nt)
          acc[mt][nt] = __builtin_amdgcn_mfma_f32_16x16x32_bf16(af[mt], bfr[nt], acc[mt][nt], 0, 0, 0);
    }
    __syncthreads();
  }
#pragma unroll
  for (int mt = 0; mt < 4; ++mt)
#pragma unroll
    for (int nt = 0; nt < 4; ++nt)
#pragma unroll
      for (int r = 0; r < 4; ++r) {
        const int row = brow + wr + mt * 16 + 4 * g + r;
        const int col = bcol + wc + nt * 16 + c;
        C[(size_t)row * N + col] = (OutT)acc[mt][nt][r];
      }
}

// ---------------------------------------------------------------- GEMM (NT, 8-phase, 3-slot)
// BM=128 x BN=256, K-half(32) staging units, 3-slot rotation, counted vmcnt(3).
// 72KB LDS -> 2 blocks/CU co-resident (cross-block overlap hides barrier lockstep).
template <typename OutT>
__global__ __launch_bounds__(512, 4) void gemm8(const bf16* __restrict__ A,
                                                const bf16* __restrict__ Bt,
                                                OutT* __restrict__ C,
                                                int N, int K, int NBX) {
  __shared__ char As[3 * 8192];
  __shared__ char Bs[3 * 16384];
  const int tid = threadIdx.x;
  const int lane = tid & 63, wid = tid >> 6;
  const int g = lane >> 4, c = lane & 15;
  const int wm = wid >> 2, wn = wid & 3;
  const int cpx = gridDim.x >> 3;
  const int wgid = ((int)blockIdx.x & 7) * cpx + ((int)blockIdx.x >> 3);
  const int by = wgid / NBX, bx = wgid % NBX;
  const int brow = by * 128, bcol = bx * 256;
  const int KH = K >> 5;

  f32x4 acc[4][4] = {};

  int LA = wid * 1024 + lane * 16;
  int lnA = LA >> 7;
  int sA = ((LA >> 4) & 7) ^ (lnA & 7);
  const char* Abase = (const char*)(A + (size_t)(brow + lnA * 2 + (sA >> 2)) * K + (sA & 3) * 8);
  int LB0 = wid * 1024 + lane * 16;
  int ln0 = LB0 >> 7;
  int s0 = ((LB0 >> 4) & 7) ^ (ln0 & 7);
  const char* Bbase0 = (const char*)(Bt + (size_t)(bcol + ln0 * 2 + (s0 >> 2)) * K + (s0 & 3) * 8);
  int LB1 = 8192 + wid * 1024 + lane * 16;
  int ln1 = LB1 >> 7;
  int s1 = ((LB1 >> 4) & 7) ^ (ln1 & 7);
  const char* Bbase1 = (const char*)(Bt + (size_t)(bcol + ln1 * 2 + (s1 >> 2)) * K + (s1 & 3) * 8);

  auto stage = [&](int kh, int slot) {
    const size_t koff = (size_t)kh * 64;
    gload16(Abase + koff, As + slot * 8192 + wid * 1024);
    gload16(Bbase0 + koff, Bs + slot * 16384 + wid * 1024);
    gload16(Bbase1 + koff, Bs + slot * 16384 + 8192 + wid * 1024);
  };

  int offA[4], offB[4];
#pragma unroll
  for (int mf = 0; mf < 4; ++mf) {
    const int row = wm * 64 + mf * 16 + c;
    const int ln = row >> 1;
    const int s = (((row & 1) << 2) | g) ^ (ln & 7);
    offA[mf] = ln * 128 + s * 16;
  }
#pragma unroll
  for (int nf = 0; nf < 4; ++nf) {
    const int row = wn * 64 + nf * 16 + c;
    const int ln = row >> 1;
    const int s = (((row & 1) << 2) | g) ^ (ln & 7);
    offB[nf] = ln * 128 + s * 16;
  }

#define GEMM8_PHASE(PHI, KHS)                                                     \
  {                                                                               \
    bf16x8 af[4], bfr[4];                                                         \
    _Pragma("unroll") for (int mf = 0; mf < 4; ++mf)                              \
      af[mf] = *(const bf16x8*)(As + (PHI) * 8192 + offA[mf]);                    \
    _Pragma("unroll") for (int nf = 0; nf < 4; ++nf)                              \
      bfr[nf] = *(const bf16x8*)(Bs + (PHI) * 16384 + offB[nf]);                  \
    stage((KHS), ((PHI) + 2) % 3);                                                \
    asm volatile("s_waitcnt vmcnt(3)" ::: "memory");                              \
    __builtin_amdgcn_s_barrier();                                                 \
    asm volatile("s_waitcnt lgkmcnt(0)" ::: "memory");                            \
    __builtin_amdgcn_sched_barrier(0);                                            \
    __builtin_amdgcn_s_setprio(1);                                                \
    _Pragma("unroll") for (int mf = 0; mf < 4; ++mf)                              \
      _Pragma("unroll") for (int nf = 0; nf < 4; ++nf)                            \
        acc[mf][nf] = __builtin_amdgcn_mfma_f32_16x16x32_bf16(af[mf], bfr[nf],    \
                                                              acc[mf][nf], 0, 0, 0); \
    __builtin_amdgcn_s_setprio(0);                                                \
    __builtin_amdgcn_s_barrier();                                                 \
  }

  stage(0, 0); stage(1, 1);
  asm volatile("s_waitcnt vmcnt(3)" ::: "memory");
  __builtin_amdgcn_s_barrier();

  const int NIT = KH / 3;
  for (int it = 0; it < NIT; ++it) {
    const int kb = it * 3;
    const int kmax = KH - 1;
    GEMM8_PHASE(0, (kb + 2 < kmax ? kb + 2 : kmax));
    GEMM8_PHASE(1, (kb + 3 < kmax ? kb + 3 : kmax));
    GEMM8_PHASE(2, (kb + 4 < kmax ? kb + 4 : kmax));
  }
#undef GEMM8_PHASE

  const int wr = wm * 64, wc = wn * 64;
#pragma unroll
  for (int mf = 0; mf < 4; ++mf)
#pragma unroll
    for (int nf = 0; nf < 4; ++nf)
#pragma unroll
      for (int r = 0; r < 4; ++r) {
        const int row = brow + wr + mf * 16 + 4 * g + r;
        const int col = bcol + wc + nf * 16 + c;
        C[(size_t)row * N + col] = (OutT)acc[mf][nf][r];
      }
}

// ------------------------------------------- RMSNorm + RoPE epilogues
__global__ __launch_bounds__(256) void nrope_q(bf16* __restrict__ q, int stride,
                                               const float* __restrict__ gw,
                                               const float* __restrict__ cache) {
  const float SC = 0.08838834764831845f * 1.4426950408889634f;
  const int w = blockIdx.x * 4 + (threadIdx.x >> 6);
  const int lane = threadIdx.x & 63;
  const int row = w / 24, head = w % 24;
  const int pos = row & 2047;
  bf16* p = q + (size_t)row * stride + head * 128;
  float x1 = (float)p[lane], x2 = (float)p[64 + lane];
  float ss = x1 * x1 + x2 * x2;
#pragma unroll
  for (int m = 32; m; m >>= 1) ss += __shfl_xor(ss, m);
  const float inv = rsqrtf(ss * (1.0f / 128.0f) + 1e-6f);
  const float xn1 = x1 * inv * gw[lane], xn2 = x2 * inv * gw[64 + lane];
  const float cs = cache[pos * 128 + lane] * SC, sn = cache[pos * 128 + 64 + lane] * SC;
  p[lane]      = (bf16)(xn1 * cs - xn2 * sn);
  p[64 + lane] = (bf16)(xn2 * cs + xn1 * sn);
}

__global__ __launch_bounds__(256) void nrope_k(const bf16* __restrict__ src, int stride, int base,
                                               bf16* __restrict__ kf,
                                               const float* __restrict__ gw,
                                               const float* __restrict__ cache,
                                               int S, int key_off) {
  const int w = blockIdx.x * 4 + (threadIdx.x >> 6);
  const int lane = threadIdx.x & 63;
  const int row = w >> 3, hkv = w & 7;
  const int b = row / S, s = row % S;
  const bf16* p = src + (size_t)row * stride + base + hkv * 128;
  float x1 = (float)p[lane], x2 = (float)p[64 + lane];
  float ss = x1 * x1 + x2 * x2;
#pragma unroll
  for (int m = 32; m; m >>= 1) ss += __shfl_xor(ss, m);
  const float inv = rsqrtf(ss * (1.0f / 128.0f) + 1e-6f);
  const float xn1 = x1 * inv * gw[lane], xn2 = x2 * inv * gw[64 + lane];
  const float cs = cache[s * 128 + lane], sn = cache[s * 128 + 64 + lane];
  bf16* o = kf + ((size_t)(b * 8 + hkv) * 2560 + key_off + s) * 128;
  const int dsw = lane ^ ((s & 7) << 3);
  o[dsw]      = (bf16)(xn1 * cs - xn2 * sn);
  o[64 + dsw] = (bf16)(xn2 * cs + xn1 * sn);
}

__global__ __launch_bounds__(256) void transpose_v(const bf16* __restrict__ src, int stride, int base,
                                                   bf16* __restrict__ vtp,
                                                   int S, int key_off) {
  __shared__ bf16 t[32][33];
  const int tid = threadIdx.x;
  const int bh = blockIdx.z;
  const int b = bh >> 3, hkv = bh & 7;
  const int s0 = blockIdx.x * 32, d0 = blockIdx.y * 32;
  const int r = tid >> 3, c4 = (tid & 7) * 4;
  bf16x4 v = *(const bf16x4*)(src + (size_t)(b * S + s0 + r) * stride + base + hkv * 128 + d0 + c4);
  t[r][c4 + 0] = v[0]; t[r][c4 + 1] = v[1]; t[r][c4 + 2] = v[2]; t[r][c4 + 3] = v[3];
  __syncthreads();
  bf16x4 o = { t[c4 + 0][r], t[c4 + 1][r], t[c4 + 2][r], t[c4 + 3][r] };
  *(bf16x4*)(vtp + ((size_t)bh * 128 + d0 + r) * 2560 + key_off + s0 + c4) = o;
}

// ---------------------------------------------------------------- attention
// 384 blocks XCD-chunked; 256 q/block, 4 waves x 64 q (4 q-tiles of 16).
// K/V frags read from LDS ONCE per iter, reused across 4 q-tiles -> MFMA/LDS ratio 2x
// (attn was LDS-BW-bound at 32 q/wave: ~4200 LDS cyc vs ~2480 MFMA cyc per CU-iter).
// KVBLK=64; K+V double-buffered; max-free softmax (RMSNorm bound |s*log2e|<=16.3).
__global__ __launch_bounds__(256, 2) void attn_kernel(const bf16* __restrict__ qf,   // [4096][5120]
                                                      const bf16* __restrict__ kfsw, // [16][2560][128] swz
                                                      const bf16* __restrict__ vtp,  // [16][128][2560]
                                                      bf16* __restrict__ attnb) {    // [4096][3072]
  __shared__ bf16 Ks[2][64 * 128];   // 2 x 16KB K tiles (global pre-swizzled, linear copy)
  __shared__ bf16 Vs[2][128 * 64];   // 2 x 16KB V^T tiles (swizzled at stage)
  __shared__ char Ps[4][1280];       // per-wave P staging, 16 rows x 80B
  const int tid = threadIdx.x;
  const int wid = tid >> 6, lane = tid & 63;
  const int g = lane >> 4, c = lane & 15;
  // XCD-chunked remap: 48 consecutive work-ids per XCD
  const int bid0 = blockIdx.x;
  const int bid  = (bid0 & 7) * 48 + (bid0 >> 3);
  const int qb = bid & 7;
  const int h  = (bid >> 3) % 24;
  const int b  = bid / 192;
  const int q0 = qb * 256 + wid * 64;     // this wave's 64 q rows (4 tiles of 16)
  const int hkv = h / 3;
  const char* kfB = (const char*)kfsw + (size_t)(b * 8 + hkv) * 2560 * 256;
  const char* vtB = (const char*)vtp  + (size_t)(b * 8 + hkv) * 128 * 5120;

  bf16x8 qfrag[4][4];
#pragma unroll
  for (int qt = 0; qt < 4; ++qt) {
    const size_t qrow = (size_t)(b * 2048 + q0 + qt * 16 + c) * 5120 + h * 128;
#pragma unroll
    for (int kc = 0; kc < 4; ++kc)
      qfrag[qt][kc] = *(const bf16x8*)(qf + qrow + kc * 32 + g * 8);
  }

  f32x4 ot[4][8] = {};
  float lsum[4] = { 0.f, 0.f, 0.f, 0.f };   // per-lane partials, g-reduced in epilogue

  auto stage = [&](int key0, int buf) {
    {
      char* ldst = (char*)&Ks[buf][0] + wid * 4096;
      const char* gsrc = kfB + (size_t)(key0 + wid * 16) * 256
                       + (lane >> 4) * 256 + (lane & 15) * 16;
#pragma unroll
      for (int j = 0; j < 4; ++j)
        gload16(gsrc + j * 1024, ldst + j * 1024);
    }
    {
      char* ldst = (char*)&Vs[buf][0] + wid * 4096;
      const int r8 = lane >> 3, c8 = lane & 7;
      const char* gsrc = vtB + (size_t)(wid * 32 + r8) * 5120 + (size_t)key0 * 2
                       + ((c8 ^ r8) * 16);
#pragma unroll
      for (int j = 0; j < 4; ++j)
        gload16(gsrc + (size_t)j * 8 * 5120, ldst + j * 1024);
    }
  };

  stage(0, 0);
  __syncthreads();

  for (int it = 0; it < 40; ++it) {
    const int cur = it & 1;
    if (it + 1 < 40) stage((it + 1) * 64, cur ^ 1);

    const char* Kb = (const char*)&Ks[cur][0];
    const char* Vb = (const char*)&Vs[cur][0];

#pragma unroll
    for (int kb = 0; kb < 2; ++kb) {
      // QK^T (swapped): K-frags read once, reused across 4 q-tiles
      f32x4 s[4][2] = {};
      __builtin_amdgcn_s_setprio(1);
#pragma unroll
      for (int kc = 0; kc < 4; ++kc) {
        const int bsw = (kc * 64 + g * 16) ^ ((c & 7) << 4);
        bf16x8 a0 = *(const bf16x8*)(Kb + (kb * 32 + c) * 256 + bsw);
        bf16x8 a1 = *(const bf16x8*)(Kb + (kb * 32 + 16 + c) * 256 + bsw);
#pragma unroll
        for (int qt = 0; qt < 4; ++qt) {
          s[qt][0] = __builtin_amdgcn_mfma_f32_16x16x32_bf16(a0, qfrag[qt][kc], s[qt][0], 0, 0, 0);
          s[qt][1] = __builtin_amdgcn_mfma_f32_16x16x32_bf16(a1, qfrag[qt][kc], s[qt][1], 0, 0, 0);
        }
      }
      __builtin_amdgcn_s_setprio(0);

      // V fragments for this key half: read once, reused across 4 q-tiles
      bf16x8 vfrag[8];
#pragma unroll
      for (int dt = 0; dt < 8; ++dt)
        vfrag[dt] = *(const bf16x8*)(Vb + (dt * 16 + c) * 128 + (((kb * 4 + g) ^ (c & 7)) * 16));

#pragma unroll
      for (int qt = 0; qt < 4; ++qt) {
        // max-free softmax: P = exp2(s) directly (bounded by 2^16.3, fp32-safe)
        float p0[4], p1[4];
#pragma unroll
        for (int r = 0; r < 4; ++r) {
          p0[r] = fexp2(s[qt][0][r]);
          p1[r] = fexp2(s[qt][1][r]);
          lsum[qt] += p0[r] + p1[r];
        }
        // P redistribution via per-wave LDS tile: row q=c (80B stride)
        uint2 w0, w1;
        w0.x = pack2bf(p0[0], p0[1]); w0.y = pack2bf(p0[2], p0[3]);
        w1.x = pack2bf(p1[0], p1[1]); w1.y = pack2bf(p1[2], p1[3]);
        *(uint2*)(&Ps[wid][0] + c * 80 + 8 * g)      = w0;   // keys 4g..4g+3
        *(uint2*)(&Ps[wid][0] + c * 80 + 32 + 8 * g) = w1;   // keys 16+4g..
        bf16x8 pf = *(const bf16x8*)(&Ps[wid][0] + c * 80 + g * 16);  // keys 8g..8g+7
        __builtin_amdgcn_s_setprio(1);
#pragma unroll
        for (int dt = 0; dt < 8; ++dt)
          ot[qt][dt] = __builtin_amdgcn_mfma_f32_16x16x32_bf16(vfrag[dt], pf, ot[qt][dt], 0, 0, 0);
        __builtin_amdgcn_s_setprio(0);
      }
    }
    __syncthreads();
  }

  // O^T[d][q] -> per-wave 16KB LDS tile (aliases Ks+Vs, dead now; swizzled) -> coalesced global
  char* osm = (char*)&Ks[0][0] + wid * 16384;
#pragma unroll
  for (int qt = 0; qt < 4; ++qt) {
    float ls = lsum[qt];
    ls += __shfl_xor(ls, 16);
    ls += __shfl_xor(ls, 32);
    const float inv = 1.0f / ls;
    const int q = qt * 16 + c;
#pragma unroll
    for (int dt = 0; dt < 8; ++dt) {
      uint2 w2;
      w2.x = pack2bf(ot[qt][dt][0] * inv, ot[qt][dt][1] * inv);
      w2.y = pack2bf(ot[qt][dt][2] * inv, ot[qt][dt][3] * inv);
      *(uint2*)(osm + q * 256 + ((dt * 32 + 8 * g) ^ ((q & 7) << 4))) = w2;
    }
  }
  __syncthreads();
#pragma unroll
  for (int it = 0; it < 16; ++it) {
    const int off = it * 1024 + lane * 16;     // byte in 16KB tile
    const int qrow = off >> 8, colb = off & 255;
    bf16x8 v = *(const bf16x8*)(osm + qrow * 256 + (colb ^ ((qrow & 7) << 4)));
    *(bf16x8*)((char*)attnb + ((size_t)(b * 2048 + q0 + qrow) * 3072 + h * 128) * 2 + colb) = v;
  }
}

// ---------------------------------------------------------------- launcher
extern "C" void kernel_launch(void* const* d_in, const int* in_sizes, int n_in,
                              void* d_out, int out_size, void* d_ws, size_t ws_size,
                              hipStream_t stream) {
  const float* hs     = (const float*)d_in[0];
  const float* ehs    = (const float*)d_in[1];
  const float* Wq     = (const float*)d_in[2];
  const float* Wk     = (const float*)d_in[3];
  const float* Wv     = (const float*)d_in[4];
  const float* Wak    = (const float*)d_in[5];
  const float* Wav    = (const float*)d_in[6];
  const float* Wo     = (const float*)d_in[7];
  const float* gq     = (const float*)d_in[8];
  const float* gk     = (const float*)d_in[9];
  const float* gak    = (const float*)d_in[10];
  const float* icache = (const float*)d_in[11];
  const float* tcache = (const float*)d_in[12];

  char* ws = (char*)d_ws;
  bf16* hsb    = (bf16*)(ws + 0);            // 25.2MB; reused as attnb after QKV GEMM
  bf16* Wcomb  = (bf16*)(ws + 25165824);     // [5120][3072] 31.5MB (Wq|Wk|Wv)^T; reused for Wot
  bf16* ehsb   = (bf16*)(ws + 56623104);     // 6.3MB; (ehsb+Wacomb region reused as vt)
  bf16* Wacomb = (bf16*)(ws + 62914560);     // [2048][3072] 12.6MB (Wak|Wav)^T
  bf16* qkvC   = (bf16*)(ws + 75497472);     // [4096][5120] 41.9MB (q|k|v)
  bf16* tC     = (bf16*)(ws + 117440512);    // [1024][2048] 4.2MB (tk|tv)
  bf16* kf     = (bf16*)(ws + 121634816);    // 10.5MB joint K [16][2560][128] (swizzled)
  bf16* Wot    = (bf16*)(ws + 25165824);     // 18.9MB, aliases Wcomb (dead after QKV GEMM)
  bf16* vt     = (bf16*)(ws + 56623104);     // 10.5MB joint V^T, aliases ehsb+Wacomb (dead after tGEMM)
  bf16* attnb  = hsb;                        // aliases hsb (dead after QKV GEMM)

  cvt_bf16<<<6144, 256, 0, stream>>>(hs, hsb, 1572864);
  cvt_bf16<<<1536, 256, 0, stream>>>(ehs, ehsb, 393216);
  tcvt<<<dim3(96, 96), 256, 0, stream>>>(Wq,  Wcomb,                3072, 3072);
  tcvt<<<dim3(32, 96), 256, 0, stream>>>(Wk,  Wcomb + 3072 * 3072,  3072, 1024);
  tcvt<<<dim3(32, 96), 256, 0, stream>>>(Wv,  Wcomb + 4096 * 3072,  3072, 1024);
  tcvt<<<dim3(32, 96), 256, 0, stream>>>(Wak, Wacomb,               3072, 1024);
  tcvt<<<dim3(32, 96), 256, 0, stream>>>(Wav, Wacomb + 1024 * 3072, 3072, 1024);

  // fused QKV GEMM (8-phase, 3-slot, 2 blk/CU): [4096][3072] x [5120][3072]^T -> [4096][5120]
  gemm8<bf16><<<640, 512, 0, stream>>>(hsb, Wcomb, qkvC, 5120, 3072, 20);
  // fused tK/tV GEMM (small): [1024][3072] x [2048][3072]^T -> [1024][2048]
  gemm_bt<bf16><<<dim3(16, 8), 256, 0, stream>>>(ehsb, Wacomb, tC, 2048, 3072);

  // Wo transpose-convert AFTER QKV GEMM (reuses Wcomb region)
  tcvt<<<dim3(96, 96), 256, 0, stream>>>(Wo, Wot, 3072, 3072);

  nrope_q<<<24576, 256, 0, stream>>>(qkvC, 5120, gq, icache);
  nrope_k<<<8192, 256, 0, stream>>>(qkvC, 5120, 3072, kf, gk,  icache, 2048, 0);
  nrope_k<<<2048, 256, 0, stream>>>(tC,   2048, 0,    kf, gak, tcache, 512,  2048);
  transpose_v<<<dim3(64, 4, 16), 256, 0, stream>>>(qkvC, 5120, 4096, vt, 2048, 0);
  transpose_v<<<dim3(16, 4, 16), 256, 0, stream>>>(tC,   2048, 1024, vt, 512,  2048);

  attn_kernel<<<384, 256, 0, stream>>>(qkvC, kf, vt, attnb);

  // out-proj GEMM (8-phase, 3-slot): [4096][3072] x [3072][3072]^T -> fp32 d_out
  gemm8<float><<<384, 512, 0, stream>>>(attnb, Wot, (float*)d_out, 3072, 3072, 12);
}

// Round 14
// 555.963 us; speedup vs baseline: 2.0720x; 2.0720x over previous
//
#include <hip/hip_runtime.h>
#include <hip/hip_bf16.h>
#include <math.h>

typedef __bf16 bf16;
typedef __bf16 bf16x4 __attribute__((ext_vector_type(4)));
typedef __bf16 bf16x8 __attribute__((ext_vector_type(8)));
typedef float  f32x4  __attribute__((ext_vector_type(4)));

typedef __attribute__((address_space(1))) void gvoid_t;
typedef __attribute__((address_space(3))) void lvoid_t;

static __device__ __forceinline__ void gload16(const void* g, void* l) {
  // async global->LDS, 16B per lane; LDS dest wave-uniform base (HW adds lane*16)
  __builtin_amdgcn_global_load_lds((gvoid_t*)g, (lvoid_t*)l, 16, 0, 0);
}

static __device__ __forceinline__ float fexp2(float x) {
  return __builtin_amdgcn_exp2f(x);   // v_exp_f32: 2^x
}

static __device__ __forceinline__ unsigned pack2bf(float lo, float hi) {
  unsigned short l = __builtin_bit_cast(unsigned short, (bf16)lo);
  unsigned short h = __builtin_bit_cast(unsigned short, (bf16)hi);
  return ((unsigned)h << 16) | (unsigned)l;
}

// ---------------------------------------------------------------- converts
__global__ __launch_bounds__(256) void cvt_bf16(const float* __restrict__ in,
                                                bf16* __restrict__ out, int n8) {
  int i = blockIdx.x * 256 + threadIdx.x;
  if (i >= n8) return;
  const float4* p = (const float4*)(in + (size_t)i * 8);
  float4 v0 = p[0], v1 = p[1];
  bf16x8 o;
  o[0] = (bf16)v0.x; o[1] = (bf16)v0.y; o[2] = (bf16)v0.z; o[3] = (bf16)v0.w;
  o[4] = (bf16)v1.x; o[5] = (bf16)v1.y; o[6] = (bf16)v1.z; o[7] = (bf16)v1.w;
  *(bf16x8*)(out + (size_t)i * 8) = o;
}

// W [K][N] fp32 -> Wt [N][K] bf16 (32x32 LDS tiles)
__global__ __launch_bounds__(256) void tcvt(const float* __restrict__ W,
                                            bf16* __restrict__ Wt, int K, int N) {
  __shared__ float t[32][33];
  const int tid = threadIdx.x;
  const int r = tid >> 3, c4 = (tid & 7) * 4;
  const size_t grow = (size_t)(blockIdx.y * 32 + r);
  float4 v = *(const float4*)(W + grow * N + blockIdx.x * 32 + c4);
  t[r][c4 + 0] = v.x; t[r][c4 + 1] = v.y; t[r][c4 + 2] = v.z; t[r][c4 + 3] = v.w;
  __syncthreads();
  bf16x4 o = { (bf16)t[c4 + 0][r], (bf16)t[c4 + 1][r], (bf16)t[c4 + 2][r], (bf16)t[c4 + 3][r] };
  *(bf16x4*)(Wt + (size_t)(blockIdx.x * 32 + r) * K + blockIdx.y * 32 + c4) = o;
}

// ---------------------------------------------------------------- GEMM (NT, small shapes)
template <typename OutT>
__global__ __launch_bounds__(256) void gemm_bt(const bf16* __restrict__ A,
                                               const bf16* __restrict__ Bt,
                                               OutT* __restrict__ C,
                                               int N, int K) {
  __shared__ bf16 As[128 * 64];
  __shared__ bf16 Bs[128 * 64];
  const int tid = threadIdx.x;
  const int wid = tid >> 6, lane = tid & 63;
  const int g = lane >> 4, c = lane & 15;
  const int brow = blockIdx.y * 128, bcol = blockIdx.x * 128;
  const int wr = (wid >> 1) * 64, wc = (wid & 1) * 64;
  f32x4 acc[4][4] = {};

  for (int k0 = 0; k0 < K; k0 += 64) {
#pragma unroll
    for (int i = 0; i < 4; ++i) {
      const int off = i * 4096 + tid * 16;
      const int row = off >> 7, colb = off & 127;
      gload16((const char*)A + ((size_t)(brow + row) * K + k0) * 2 + colb,
              (char*)As + i * 4096 + wid * 1024);
      gload16((const char*)Bt + ((size_t)(bcol + row) * K + k0) * 2 + colb,
              (char*)Bs + i * 4096 + wid * 1024);
    }
    __syncthreads();
#pragma unroll
    for (int ks = 0; ks < 2; ++ks) {
      bf16x8 af[4], bfr[4];
#pragma unroll
      for (int t = 0; t < 4; ++t) {
        af[t]  = *(const bf16x8*)(As + (wr + t * 16 + c) * 64 + ks * 32 + g * 8);
        bfr[t] = *(const bf16x8*)(Bs + (wc + t * 16 + c) * 64 + ks * 32 + g * 8);
      }
#pragma unroll
      for (int mt = 0; mt < 4; ++mt)
#pragma unroll
        for (int nt = 0; nt < 4; ++nt)
          acc[mt][nt] = __builtin_amdgcn_mfma_f32_16x16x32_bf16(af[mt], bfr[nt], acc[mt][nt], 0, 0, 0);
    }
    __syncthreads();
  }
#pragma unroll
  for (int mt = 0; mt < 4; ++mt)
#pragma unroll
    for (int nt = 0; nt < 4; ++nt)
#pragma unroll
      for (int r = 0; r < 4; ++r) {
        const int row = brow + wr + mt * 16 + 4 * g + r;
        const int col = bcol + wc + nt * 16 + c;
        C[(size_t)row * N + col] = (OutT)acc[mt][nt][r];
      }
}

// ---------------------------------------------------------------- GEMM (NT, 8-phase, 3-slot)
// BM=128 x BN=256, K-half(32) staging units, 3-slot rotation, counted vmcnt(3).
// 72KB LDS -> 2 blocks/CU co-resident. XCD mapping: 16by x (NBX/4)bx 2D tile per XCD
// (R12 was 4by x NBX: per-XCD fill 34.5MB -> 2.2TB/s L2-fill-BOUND; 16x5 tile = 20.5MB).
// Requires NBY == 32, NBX % 4 == 0 (QKV: 32x20; out-proj: 32x12).
template <typename OutT>
__global__ __launch_bounds__(512, 4) void gemm8(const bf16* __restrict__ A,
                                                const bf16* __restrict__ Bt,
                                                OutT* __restrict__ C,
                                                int N, int K, int NBX) {
  __shared__ char As[3 * 8192];
  __shared__ char Bs[3 * 16384];
  const int tid = threadIdx.x;
  const int lane = tid & 63, wid = tid >> 6;
  const int g = lane >> 4, c = lane & 15;
  const int wm = wid >> 2, wn = wid & 3;
  // 2D XCD tile: xcd owns by in [ (xcd>>2)*16, +16 ), bx in [ (xcd&3)*(NBX/4), +NBX/4 )
  const int xcd = (int)blockIdx.x & 7;
  const int local = (int)blockIdx.x >> 3;
  const int by = (xcd >> 2) * 16 + (local & 15);
  const int bx = (xcd & 3) * (NBX >> 2) + (local >> 4);
  const int brow = by * 128, bcol = bx * 256;
  const int KH = K >> 5;

  f32x4 acc[4][4] = {};

  int LA = wid * 1024 + lane * 16;
  int lnA = LA >> 7;
  int sA = ((LA >> 4) & 7) ^ (lnA & 7);
  const char* Abase = (const char*)(A + (size_t)(brow + lnA * 2 + (sA >> 2)) * K + (sA & 3) * 8);
  int LB0 = wid * 1024 + lane * 16;
  int ln0 = LB0 >> 7;
  int s0 = ((LB0 >> 4) & 7) ^ (ln0 & 7);
  const char* Bbase0 = (const char*)(Bt + (size_t)(bcol + ln0 * 2 + (s0 >> 2)) * K + (s0 & 3) * 8);
  int LB1 = 8192 + wid * 1024 + lane * 16;
  int ln1 = LB1 >> 7;
  int s1 = ((LB1 >> 4) & 7) ^ (ln1 & 7);
  const char* Bbase1 = (const char*)(Bt + (size_t)(bcol + ln1 * 2 + (s1 >> 2)) * K + (s1 & 3) * 8);

  auto stage = [&](int kh, int slot) {
    const size_t koff = (size_t)kh * 64;
    gload16(Abase + koff, As + slot * 8192 + wid * 1024);
    gload16(Bbase0 + koff, Bs + slot * 16384 + wid * 1024);
    gload16(Bbase1 + koff, Bs + slot * 16384 + 8192 + wid * 1024);
  };

  int offA[4], offB[4];
#pragma unroll
  for (int mf = 0; mf < 4; ++mf) {
    const int row = wm * 64 + mf * 16 + c;
    const int ln = row >> 1;
    const int s = (((row & 1) << 2) | g) ^ (ln & 7);
    offA[mf] = ln * 128 + s * 16;
  }
#pragma unroll
  for (int nf = 0; nf < 4; ++nf) {
    const int row = wn * 64 + nf * 16 + c;
    const int ln = row >> 1;
    const int s = (((row & 1) << 2) | g) ^ (ln & 7);
    offB[nf] = ln * 128 + s * 16;
  }

#define GEMM8_PHASE(PHI, KHS)                                                     \
  {                                                                               \
    bf16x8 af[4], bfr[4];                                                         \
    _Pragma("unroll") for (int mf = 0; mf < 4; ++mf)                              \
      af[mf] = *(const bf16x8*)(As + (PHI) * 8192 + offA[mf]);                    \
    _Pragma("unroll") for (int nf = 0; nf < 4; ++nf)                              \
      bfr[nf] = *(const bf16x8*)(Bs + (PHI) * 16384 + offB[nf]);                  \
    stage((KHS), ((PHI) + 2) % 3);                                                \
    asm volatile("s_waitcnt vmcnt(3)" ::: "memory");                              \
    __builtin_amdgcn_s_barrier();                                                 \
    asm volatile("s_waitcnt lgkmcnt(0)" ::: "memory");                            \
    __builtin_amdgcn_sched_barrier(0);                                            \
    __builtin_amdgcn_s_setprio(1);                                                \
    _Pragma("unroll") for (int mf = 0; mf < 4; ++mf)                              \
      _Pragma("unroll") for (int nf = 0; nf < 4; ++nf)                            \
        acc[mf][nf] = __builtin_amdgcn_mfma_f32_16x16x32_bf16(af[mf], bfr[nf],    \
                                                              acc[mf][nf], 0, 0, 0); \
    __builtin_amdgcn_s_setprio(0);                                                \
    __builtin_amdgcn_s_barrier();                                                 \
  }

  stage(0, 0); stage(1, 1);
  asm volatile("s_waitcnt vmcnt(3)" ::: "memory");
  __builtin_amdgcn_s_barrier();

  const int NIT = KH / 3;
  for (int it = 0; it < NIT; ++it) {
    const int kb = it * 3;
    const int kmax = KH - 1;
    GEMM8_PHASE(0, (kb + 2 < kmax ? kb + 2 : kmax));
    GEMM8_PHASE(1, (kb + 3 < kmax ? kb + 3 : kmax));
    GEMM8_PHASE(2, (kb + 4 < kmax ? kb + 4 : kmax));
  }
#undef GEMM8_PHASE

  const int wr = wm * 64, wc = wn * 64;
#pragma unroll
  for (int mf = 0; mf < 4; ++mf)
#pragma unroll
    for (int nf = 0; nf < 4; ++nf)
#pragma unroll
      for (int r = 0; r < 4; ++r) {
        const int row = brow + wr + mf * 16 + 4 * g + r;
        const int col = bcol + wc + nf * 16 + c;
        C[(size_t)row * N + col] = (OutT)acc[mf][nf][r];
      }
}

// ------------------------------------------- RMSNorm + RoPE epilogues
__global__ __launch_bounds__(256) void nrope_q(bf16* __restrict__ q, int stride,
                                               const float* __restrict__ gw,
                                               const float* __restrict__ cache) {
  const float SC = 0.08838834764831845f * 1.4426950408889634f;
  const int w = blockIdx.x * 4 + (threadIdx.x >> 6);
  const int lane = threadIdx.x & 63;
  const int row = w / 24, head = w % 24;
  const int pos = row & 2047;
  bf16* p = q + (size_t)row * stride + head * 128;
  float x1 = (float)p[lane], x2 = (float)p[64 + lane];
  float ss = x1 * x1 + x2 * x2;
#pragma unroll
  for (int m = 32; m; m >>= 1) ss += __shfl_xor(ss, m);
  const float inv = rsqrtf(ss * (1.0f / 128.0f) + 1e-6f);
  const float xn1 = x1 * inv * gw[lane], xn2 = x2 * inv * gw[64 + lane];
  const float cs = cache[pos * 128 + lane] * SC, sn = cache[pos * 128 + 64 + lane] * SC;
  p[lane]      = (bf16)(xn1 * cs - xn2 * sn);
  p[64 + lane] = (bf16)(xn2 * cs + xn1 * sn);
}

__global__ __launch_bounds__(256) void nrope_k(const bf16* __restrict__ src, int stride, int base,
                                               bf16* __restrict__ kf,
                                               const float* __restrict__ gw,
                                               const float* __restrict__ cache,
                                               int S, int key_off) {
  const int w = blockIdx.x * 4 + (threadIdx.x >> 6);
  const int lane = threadIdx.x & 63;
  const int row = w >> 3, hkv = w & 7;
  const int b = row / S, s = row % S;
  const bf16* p = src + (size_t)row * stride + base + hkv * 128;
  float x1 = (float)p[lane], x2 = (float)p[64 + lane];
  float ss = x1 * x1 + x2 * x2;
#pragma unroll
  for (int m = 32; m; m >>= 1) ss += __shfl_xor(ss, m);
  const float inv = rsqrtf(ss * (1.0f / 128.0f) + 1e-6f);
  const float xn1 = x1 * inv * gw[lane], xn2 = x2 * inv * gw[64 + lane];
  const float cs = cache[s * 128 + lane], sn = cache[s * 128 + 64 + lane];
  bf16* o = kf + ((size_t)(b * 8 + hkv) * 2560 + key_off + s) * 128;
  const int dsw = lane ^ ((s & 7) << 3);
  o[dsw]      = (bf16)(xn1 * cs - xn2 * sn);
  o[64 + dsw] = (bf16)(xn2 * cs + xn1 * sn);
}

__global__ __launch_bounds__(256) void transpose_v(const bf16* __restrict__ src, int stride, int base,
                                                   bf16* __restrict__ vtp,
                                                   int S, int key_off) {
  __shared__ bf16 t[32][33];
  const int tid = threadIdx.x;
  const int bh = blockIdx.z;
  const int b = bh >> 3, hkv = bh & 7;
  const int s0 = blockIdx.x * 32, d0 = blockIdx.y * 32;
  const int r = tid >> 3, c4 = (tid & 7) * 4;
  bf16x4 v = *(const bf16x4*)(src + (size_t)(b * S + s0 + r) * stride + base + hkv * 128 + d0 + c4);
  t[r][c4 + 0] = v[0]; t[r][c4 + 1] = v[1]; t[r][c4 + 2] = v[2]; t[r][c4 + 3] = v[3];
  __syncthreads();
  bf16x4 o = { t[c4 + 0][r], t[c4 + 1][r], t[c4 + 2][r], t[c4 + 3][r] };
  *(bf16x4*)(vtp + ((size_t)bh * 128 + d0 + r) * 2560 + key_off + s0 + c4) = o;
}

// ---------------------------------------------------------------- attention (R12 known-good)
// 768 blocks XCD-chunked; 128 q/block, 4 waves x 32 q (2 q-tiles); KVBLK=64; K+V dbuf.
// Max-free softmax. 104 VGPR measured — do NOT widen to 4 q-tiles (R13: 280-reg spill).
__global__ __launch_bounds__(256, 2) void attn_kernel(const bf16* __restrict__ qf,   // [4096][5120]
                                                      const bf16* __restrict__ kfsw, // [16][2560][128] swz
                                                      const bf16* __restrict__ vtp,  // [16][128][2560]
                                                      bf16* __restrict__ attnb) {    // [4096][3072]
  __shared__ bf16 Ks[2][64 * 128];
  __shared__ bf16 Vs[2][128 * 64];
  __shared__ char Ps[4][1280];
  const int tid = threadIdx.x;
  const int wid = tid >> 6, lane = tid & 63;
  const int g = lane >> 4, c = lane & 15;
  const int bid0 = blockIdx.x;
  const int bid  = (bid0 & 7) * 96 + (bid0 >> 3);
  const int qb = bid & 15;
  const int h  = (bid >> 4) % 24;
  const int b  = bid / 384;
  const int q0 = qb * 128 + wid * 32;
  const int hkv = h / 3;
  const char* kfB = (const char*)kfsw + (size_t)(b * 8 + hkv) * 2560 * 256;
  const char* vtB = (const char*)vtp  + (size_t)(b * 8 + hkv) * 128 * 5120;

  bf16x8 qfrag[2][4];
#pragma unroll
  for (int qt = 0; qt < 2; ++qt) {
    const size_t qrow = (size_t)(b * 2048 + q0 + qt * 16 + c) * 5120 + h * 128;
#pragma unroll
    for (int kc = 0; kc < 4; ++kc)
      qfrag[qt][kc] = *(const bf16x8*)(qf + qrow + kc * 32 + g * 8);
  }

  f32x4 ot[2][8] = {};
  float lsum[2] = { 0.f, 0.f };

  auto stage = [&](int key0, int buf) {
    {
      char* ldst = (char*)&Ks[buf][0] + wid * 4096;
      const char* gsrc = kfB + (size_t)(key0 + wid * 16) * 256
                       + (lane >> 4) * 256 + (lane & 15) * 16;
#pragma unroll
      for (int j = 0; j < 4; ++j)
        gload16(gsrc + j * 1024, ldst + j * 1024);
    }
    {
      char* ldst = (char*)&Vs[buf][0] + wid * 4096;
      const int r8 = lane >> 3, c8 = lane & 7;
      const char* gsrc = vtB + (size_t)(wid * 32 + r8) * 5120 + (size_t)key0 * 2
                       + ((c8 ^ r8) * 16);
#pragma unroll
      for (int j = 0; j < 4; ++j)
        gload16(gsrc + (size_t)j * 8 * 5120, ldst + j * 1024);
    }
  };

  stage(0, 0);
  __syncthreads();

  for (int it = 0; it < 40; ++it) {
    const int cur = it & 1;
    if (it + 1 < 40) stage((it + 1) * 64, cur ^ 1);

    const char* Kb = (const char*)&Ks[cur][0];
    const char* Vb = (const char*)&Vs[cur][0];

#pragma unroll
    for (int kb = 0; kb < 2; ++kb) {
      f32x4 s[2][2] = {};
      __builtin_amdgcn_s_setprio(1);
#pragma unroll
      for (int kc = 0; kc < 4; ++kc) {
        const int bsw = (kc * 64 + g * 16) ^ ((c & 7) << 4);
        bf16x8 a0 = *(const bf16x8*)(Kb + (kb * 32 + c) * 256 + bsw);
        bf16x8 a1 = *(const bf16x8*)(Kb + (kb * 32 + 16 + c) * 256 + bsw);
#pragma unroll
        for (int qt = 0; qt < 2; ++qt) {
          s[qt][0] = __builtin_amdgcn_mfma_f32_16x16x32_bf16(a0, qfrag[qt][kc], s[qt][0], 0, 0, 0);
          s[qt][1] = __builtin_amdgcn_mfma_f32_16x16x32_bf16(a1, qfrag[qt][kc], s[qt][1], 0, 0, 0);
        }
      }
      __builtin_amdgcn_s_setprio(0);

      bf16x8 vfrag[8];
#pragma unroll
      for (int dt = 0; dt < 8; ++dt)
        vfrag[dt] = *(const bf16x8*)(Vb + (dt * 16 + c) * 128 + (((kb * 4 + g) ^ (c & 7)) * 16));

#pragma unroll
      for (int qt = 0; qt < 2; ++qt) {
        float p0[4], p1[4];
#pragma unroll
        for (int r = 0; r < 4; ++r) {
          p0[r] = fexp2(s[qt][0][r]);
          p1[r] = fexp2(s[qt][1][r]);
          lsum[qt] += p0[r] + p1[r];
        }
        uint2 w0, w1;
        w0.x = pack2bf(p0[0], p0[1]); w0.y = pack2bf(p0[2], p0[3]);
        w1.x = pack2bf(p1[0], p1[1]); w1.y = pack2bf(p1[2], p1[3]);
        *(uint2*)(&Ps[wid][0] + c * 80 + 8 * g)      = w0;
        *(uint2*)(&Ps[wid][0] + c * 80 + 32 + 8 * g) = w1;
        bf16x8 pf = *(const bf16x8*)(&Ps[wid][0] + c * 80 + g * 16);
        __builtin_amdgcn_s_setprio(1);
#pragma unroll
        for (int dt = 0; dt < 8; ++dt)
          ot[qt][dt] = __builtin_amdgcn_mfma_f32_16x16x32_bf16(vfrag[dt], pf, ot[qt][dt], 0, 0, 0);
        __builtin_amdgcn_s_setprio(0);
      }
    }
    __syncthreads();
  }

  char* osm = (char*)&Ks[0][0] + wid * 8192;
#pragma unroll
  for (int qt = 0; qt < 2; ++qt) {
    float ls = lsum[qt];
    ls += __shfl_xor(ls, 16);
    ls += __shfl_xor(ls, 32);
    const float inv = 1.0f / ls;
    const int q = qt * 16 + c;
#pragma unroll
    for (int dt = 0; dt < 8; ++dt) {
      uint2 w2;
      w2.x = pack2bf(ot[qt][dt][0] * inv, ot[qt][dt][1] * inv);
      w2.y = pack2bf(ot[qt][dt][2] * inv, ot[qt][dt][3] * inv);
      *(uint2*)(osm + q * 256 + ((dt * 32 + 8 * g) ^ ((q & 7) << 4))) = w2;
    }
  }
  __syncthreads();
#pragma unroll
  for (int it = 0; it < 8; ++it) {
    const int off = it * 1024 + lane * 16;
    const int qrow = off >> 8, colb = off & 255;
    bf16x8 v = *(const bf16x8*)(osm + qrow * 256 + (colb ^ ((qrow & 7) << 4)));
    *(bf16x8*)((char*)attnb + ((size_t)(b * 2048 + q0 + qrow) * 3072 + h * 128) * 2 + colb) = v;
  }
}

// ---------------------------------------------------------------- launcher
extern "C" void kernel_launch(void* const* d_in, const int* in_sizes, int n_in,
                              void* d_out, int out_size, void* d_ws, size_t ws_size,
                              hipStream_t stream) {
  const float* hs     = (const float*)d_in[0];
  const float* ehs    = (const float*)d_in[1];
  const float* Wq     = (const float*)d_in[2];
  const float* Wk     = (const float*)d_in[3];
  const float* Wv     = (const float*)d_in[4];
  const float* Wak    = (const float*)d_in[5];
  const float* Wav    = (const float*)d_in[6];
  const float* Wo     = (const float*)d_in[7];
  const float* gq     = (const float*)d_in[8];
  const float* gk     = (const float*)d_in[9];
  const float* gak    = (const float*)d_in[10];
  const float* icache = (const float*)d_in[11];
  const float* tcache = (const float*)d_in[12];

  char* ws = (char*)d_ws;
  bf16* hsb    = (bf16*)(ws + 0);            // 25.2MB; reused as attnb after QKV GEMM
  bf16* Wcomb  = (bf16*)(ws + 25165824);     // [5120][3072] 31.5MB (Wq|Wk|Wv)^T; reused for Wot
  bf16* ehsb   = (bf16*)(ws + 56623104);     // 6.3MB; (ehsb+Wacomb region reused as vt)
  bf16* Wacomb = (bf16*)(ws + 62914560);     // [2048][3072] 12.6MB (Wak|Wav)^T
  bf16* qkvC   = (bf16*)(ws + 75497472);     // [4096][5120] 41.9MB (q|k|v)
  bf16* tC     = (bf16*)(ws + 117440512);    // [1024][2048] 4.2MB (tk|tv)
  bf16* kf     = (bf16*)(ws + 121634816);    // 10.5MB joint K [16][2560][128] (swizzled)
  bf16* Wot    = (bf16*)(ws + 25165824);     // 18.9MB, aliases Wcomb (dead after QKV GEMM)
  bf16* vt     = (bf16*)(ws + 56623104);     // 10.5MB joint V^T, aliases ehsb+Wacomb (dead after tGEMM)
  bf16* attnb  = hsb;                        // aliases hsb (dead after QKV GEMM)

  cvt_bf16<<<6144, 256, 0, stream>>>(hs, hsb, 1572864);
  cvt_bf16<<<1536, 256, 0, stream>>>(ehs, ehsb, 393216);
  tcvt<<<dim3(96, 96), 256, 0, stream>>>(Wq,  Wcomb,                3072, 3072);
  tcvt<<<dim3(32, 96), 256, 0, stream>>>(Wk,  Wcomb + 3072 * 3072,  3072, 1024);
  tcvt<<<dim3(32, 96), 256, 0, stream>>>(Wv,  Wcomb + 4096 * 3072,  3072, 1024);
  tcvt<<<dim3(32, 96), 256, 0, stream>>>(Wak, Wacomb,               3072, 1024);
  tcvt<<<dim3(32, 96), 256, 0, stream>>>(Wav, Wacomb + 1024 * 3072, 3072, 1024);

  // fused QKV GEMM (8-phase, 3-slot, 2D XCD tile): [4096][3072] x [5120][3072]^T -> [4096][5120]
  gemm8<bf16><<<640, 512, 0, stream>>>(hsb, Wcomb, qkvC, 5120, 3072, 20);
  // fused tK/tV GEMM (small): [1024][3072] x [2048][3072]^T -> [1024][2048]
  gemm_bt<bf16><<<dim3(16, 8), 256, 0, stream>>>(ehsb, Wacomb, tC, 2048, 3072);

  // Wo transpose-convert AFTER QKV GEMM (reuses Wcomb region)
  tcvt<<<dim3(96, 96), 256, 0, stream>>>(Wo, Wot, 3072, 3072);

  nrope_q<<<24576, 256, 0, stream>>>(qkvC, 5120, gq, icache);
  nrope_k<<<8192, 256, 0, stream>>>(qkvC, 5120, 3072, kf, gk,  icache, 2048, 0);
  nrope_k<<<2048, 256, 0, stream>>>(tC,   2048, 0,    kf, gak, tcache, 512,  2048);
  transpose_v<<<dim3(64, 4, 16), 256, 0, stream>>>(qkvC, 5120, 4096, vt, 2048, 0);
  transpose_v<<<dim3(16, 4, 16), 256, 0, stream>>>(tC,   2048, 1024, vt, 512,  2048);

  attn_kernel<<<768, 256, 0, stream>>>(qkvC, kf, vt, attnb);

  // out-proj GEMM (8-phase, 3-slot, 2D XCD tile): [4096][3072] x [3072][3072]^T -> fp32 d_out
  gemm8<float><<<384, 512, 0, stream>>>(attnb, Wot, (float*)d_out, 3072, 3072, 12);
}

// Round 15
// 555.028 us; speedup vs baseline: 2.0755x; 1.0017x over previous
//
#include <hip/hip_runtime.h>
#include <hip/hip_bf16.h>
#include <math.h>

typedef __bf16 bf16;
typedef __bf16 bf16x4 __attribute__((ext_vector_type(4)));
typedef __bf16 bf16x8 __attribute__((ext_vector_type(8)));
typedef float  f32x4  __attribute__((ext_vector_type(4)));

typedef __attribute__((address_space(1))) void gvoid_t;
typedef __attribute__((address_space(3))) void lvoid_t;

static __device__ __forceinline__ void gload16(const void* g, void* l) {
  // async global->LDS, 16B per lane; LDS dest wave-uniform base (HW adds lane*16)
  __builtin_amdgcn_global_load_lds((gvoid_t*)g, (lvoid_t*)l, 16, 0, 0);
}

static __device__ __forceinline__ float fexp2(float x) {
  return __builtin_amdgcn_exp2f(x);   // v_exp_f32: 2^x
}

static __device__ __forceinline__ unsigned pack2bf(float lo, float hi) {
  unsigned short l = __builtin_bit_cast(unsigned short, (bf16)lo);
  unsigned short h = __builtin_bit_cast(unsigned short, (bf16)hi);
  return ((unsigned)h << 16) | (unsigned)l;
}

// ---------------------------------------------------------------- converts
__global__ __launch_bounds__(256) void cvt_bf16(const float* __restrict__ in,
                                                bf16* __restrict__ out, int n8) {
  int i = blockIdx.x * 256 + threadIdx.x;
  if (i >= n8) return;
  const float4* p = (const float4*)(in + (size_t)i * 8);
  float4 v0 = p[0], v1 = p[1];
  bf16x8 o;
  o[0] = (bf16)v0.x; o[1] = (bf16)v0.y; o[2] = (bf16)v0.z; o[3] = (bf16)v0.w;
  o[4] = (bf16)v1.x; o[5] = (bf16)v1.y; o[6] = (bf16)v1.z; o[7] = (bf16)v1.w;
  *(bf16x8*)(out + (size_t)i * 8) = o;
}

// W [K][N] fp32 -> Wt [N][K] bf16 (32x32 LDS tiles)
__global__ __launch_bounds__(256) void tcvt(const float* __restrict__ W,
                                            bf16* __restrict__ Wt, int K, int N) {
  __shared__ float t[32][33];
  const int tid = threadIdx.x;
  const int r = tid >> 3, c4 = (tid & 7) * 4;
  const size_t grow = (size_t)(blockIdx.y * 32 + r);
  float4 v = *(const float4*)(W + grow * N + blockIdx.x * 32 + c4);
  t[r][c4 + 0] = v.x; t[r][c4 + 1] = v.y; t[r][c4 + 2] = v.z; t[r][c4 + 3] = v.w;
  __syncthreads();
  bf16x4 o = { (bf16)t[c4 + 0][r], (bf16)t[c4 + 1][r], (bf16)t[c4 + 2][r], (bf16)t[c4 + 3][r] };
  *(bf16x4*)(Wt + (size_t)(blockIdx.x * 32 + r) * K + blockIdx.y * 32 + c4) = o;
}

// ---------------------------------------------------------------- GEMM (NT, small shapes)
template <typename OutT>
__global__ __launch_bounds__(256) void gemm_bt(const bf16* __restrict__ A,
                                               const bf16* __restrict__ Bt,
                                               OutT* __restrict__ C,
                                               int N, int K) {
  __shared__ bf16 As[128 * 64];
  __shared__ bf16 Bs[128 * 64];
  const int tid = threadIdx.x;
  const int wid = tid >> 6, lane = tid & 63;
  const int g = lane >> 4, c = lane & 15;
  const int brow = blockIdx.y * 128, bcol = blockIdx.x * 128;
  const int wr = (wid >> 1) * 64, wc = (wid & 1) * 64;
  f32x4 acc[4][4] = {};

  for (int k0 = 0; k0 < K; k0 += 64) {
#pragma unroll
    for (int i = 0; i < 4; ++i) {
      const int off = i * 4096 + tid * 16;
      const int row = off >> 7, colb = off & 127;
      gload16((const char*)A + ((size_t)(brow + row) * K + k0) * 2 + colb,
              (char*)As + i * 4096 + wid * 1024);
      gload16((const char*)Bt + ((size_t)(bcol + row) * K + k0) * 2 + colb,
              (char*)Bs + i * 4096 + wid * 1024);
    }
    __syncthreads();
#pragma unroll
    for (int ks = 0; ks < 2; ++ks) {
      bf16x8 af[4], bfr[4];
#pragma unroll
      for (int t = 0; t < 4; ++t) {
        af[t]  = *(const bf16x8*)(As + (wr + t * 16 + c) * 64 + ks * 32 + g * 8);
        bfr[t] = *(const bf16x8*)(Bs + (wc + t * 16 + c) * 64 + ks * 32 + g * 8);
      }
#pragma unroll
      for (int mt = 0; mt < 4; ++mt)
#pragma unroll
        for (int nt = 0; nt < 4; ++nt)
          acc[mt][nt] = __builtin_amdgcn_mfma_f32_16x16x32_bf16(af[mt], bfr[nt], acc[mt][nt], 0, 0, 0);
    }
    __syncthreads();
  }
#pragma unroll
  for (int mt = 0; mt < 4; ++mt)
#pragma unroll
    for (int nt = 0; nt < 4; ++nt)
#pragma unroll
      for (int r = 0; r < 4; ++r) {
        const int row = brow + wr + mt * 16 + 4 * g + r;
        const int col = bcol + wc + nt * 16 + c;
        C[(size_t)row * N + col] = (OutT)acc[mt][nt][r];
      }
}

// ---------------------------------------------------------------- GEMM (NT, 8-phase, 3-slot)
// BM=128 x BN=256, K-half(32) staging units, 3-slot rotation, counted vmcnt(3).
// 72KB LDS -> 2 blocks/CU co-resident. 2D XCD tile: 16by x (NBX/4)bx per XCD.
template <typename OutT>
__global__ __launch_bounds__(512, 4) void gemm8(const bf16* __restrict__ A,
                                                const bf16* __restrict__ Bt,
                                                OutT* __restrict__ C,
                                                int N, int K, int NBX) {
  __shared__ char As[3 * 8192];
  __shared__ char Bs[3 * 16384];
  const int tid = threadIdx.x;
  const int lane = tid & 63, wid = tid >> 6;
  const int g = lane >> 4, c = lane & 15;
  const int wm = wid >> 2, wn = wid & 3;
  const int xcd = (int)blockIdx.x & 7;
  const int local = (int)blockIdx.x >> 3;
  const int by = (xcd >> 2) * 16 + (local & 15);
  const int bx = (xcd & 3) * (NBX >> 2) + (local >> 4);
  const int brow = by * 128, bcol = bx * 256;
  const int KH = K >> 5;

  f32x4 acc[4][4] = {};

  int LA = wid * 1024 + lane * 16;
  int lnA = LA >> 7;
  int sA = ((LA >> 4) & 7) ^ (lnA & 7);
  const char* Abase = (const char*)(A + (size_t)(brow + lnA * 2 + (sA >> 2)) * K + (sA & 3) * 8);
  int LB0 = wid * 1024 + lane * 16;
  int ln0 = LB0 >> 7;
  int s0 = ((LB0 >> 4) & 7) ^ (ln0 & 7);
  const char* Bbase0 = (const char*)(Bt + (size_t)(bcol + ln0 * 2 + (s0 >> 2)) * K + (s0 & 3) * 8);
  int LB1 = 8192 + wid * 1024 + lane * 16;
  int ln1 = LB1 >> 7;
  int s1 = ((LB1 >> 4) & 7) ^ (ln1 & 7);
  const char* Bbase1 = (const char*)(Bt + (size_t)(bcol + ln1 * 2 + (s1 >> 2)) * K + (s1 & 3) * 8);

  auto stage = [&](int kh, int slot) {
    const size_t koff = (size_t)kh * 64;
    gload16(Abase + koff, As + slot * 8192 + wid * 1024);
    gload16(Bbase0 + koff, Bs + slot * 16384 + wid * 1024);
    gload16(Bbase1 + koff, Bs + slot * 16384 + 8192 + wid * 1024);
  };

  int offA[4], offB[4];
#pragma unroll
  for (int mf = 0; mf < 4; ++mf) {
    const int row = wm * 64 + mf * 16 + c;
    const int ln = row >> 1;
    const int s = (((row & 1) << 2) | g) ^ (ln & 7);
    offA[mf] = ln * 128 + s * 16;
  }
#pragma unroll
  for (int nf = 0; nf < 4; ++nf) {
    const int row = wn * 64 + nf * 16 + c;
    const int ln = row >> 1;
    const int s = (((row & 1) << 2) | g) ^ (ln & 7);
    offB[nf] = ln * 128 + s * 16;
  }

#define GEMM8_PHASE(PHI, KHS)                                                     \
  {                                                                               \
    bf16x8 af[4], bfr[4];                                                         \
    _Pragma("unroll") for (int mf = 0; mf < 4; ++mf)                              \
      af[mf] = *(const bf16x8*)(As + (PHI) * 8192 + offA[mf]);                    \
    _Pragma("unroll") for (int nf = 0; nf < 4; ++nf)                              \
      bfr[nf] = *(const bf16x8*)(Bs + (PHI) * 16384 + offB[nf]);                  \
    stage((KHS), ((PHI) + 2) % 3);                                                \
    asm volatile("s_waitcnt vmcnt(3)" ::: "memory");                              \
    __builtin_amdgcn_s_barrier();                                                 \
    asm volatile("s_waitcnt lgkmcnt(0)" ::: "memory");                            \
    __builtin_amdgcn_sched_barrier(0);                                            \
    __builtin_amdgcn_s_setprio(1);                                                \
    _Pragma("unroll") for (int mf = 0; mf < 4; ++mf)                              \
      _Pragma("unroll") for (int nf = 0; nf < 4; ++nf)                            \
        acc[mf][nf] = __builtin_amdgcn_mfma_f32_16x16x32_bf16(af[mf], bfr[nf],    \
                                                              acc[mf][nf], 0, 0, 0); \
    __builtin_amdgcn_s_setprio(0);                                                \
    __builtin_amdgcn_s_barrier();                                                 \
  }

  stage(0, 0); stage(1, 1);
  asm volatile("s_waitcnt vmcnt(3)" ::: "memory");
  __builtin_amdgcn_s_barrier();

  const int NIT = KH / 3;
  for (int it = 0; it < NIT; ++it) {
    const int kb = it * 3;
    const int kmax = KH - 1;
    GEMM8_PHASE(0, (kb + 2 < kmax ? kb + 2 : kmax));
    GEMM8_PHASE(1, (kb + 3 < kmax ? kb + 3 : kmax));
    GEMM8_PHASE(2, (kb + 4 < kmax ? kb + 4 : kmax));
  }
#undef GEMM8_PHASE

  const int wr = wm * 64, wc = wn * 64;
#pragma unroll
  for (int mf = 0; mf < 4; ++mf)
#pragma unroll
    for (int nf = 0; nf < 4; ++nf)
#pragma unroll
      for (int r = 0; r < 4; ++r) {
        const int row = brow + wr + mf * 16 + 4 * g + r;
        const int col = bcol + wc + nf * 16 + c;
        C[(size_t)row * N + col] = (OutT)acc[mf][nf][r];
      }
}

// ------------------------------------------- RMSNorm + RoPE epilogues
__global__ __launch_bounds__(256) void nrope_q(bf16* __restrict__ q, int stride,
                                               const float* __restrict__ gw,
                                               const float* __restrict__ cache) {
  const float SC = 0.08838834764831845f * 1.4426950408889634f;
  const int w = blockIdx.x * 4 + (threadIdx.x >> 6);
  const int lane = threadIdx.x & 63;
  const int row = w / 24, head = w % 24;
  const int pos = row & 2047;
  bf16* p = q + (size_t)row * stride + head * 128;
  float x1 = (float)p[lane], x2 = (float)p[64 + lane];
  float ss = x1 * x1 + x2 * x2;
#pragma unroll
  for (int m = 32; m; m >>= 1) ss += __shfl_xor(ss, m);
  const float inv = rsqrtf(ss * (1.0f / 128.0f) + 1e-6f);
  const float xn1 = x1 * inv * gw[lane], xn2 = x2 * inv * gw[64 + lane];
  const float cs = cache[pos * 128 + lane] * SC, sn = cache[pos * 128 + 64 + lane] * SC;
  p[lane]      = (bf16)(xn1 * cs - xn2 * sn);
  p[64 + lane] = (bf16)(xn2 * cs + xn1 * sn);
}

__global__ __launch_bounds__(256) void nrope_k(const bf16* __restrict__ src, int stride, int base,
                                               bf16* __restrict__ kf,
                                               const float* __restrict__ gw,
                                               const float* __restrict__ cache,
                                               int S, int key_off) {
  const int w = blockIdx.x * 4 + (threadIdx.x >> 6);
  const int lane = threadIdx.x & 63;
  const int row = w >> 3, hkv = w & 7;
  const int b = row / S, s = row % S;
  const bf16* p = src + (size_t)row * stride + base + hkv * 128;
  float x1 = (float)p[lane], x2 = (float)p[64 + lane];
  float ss = x1 * x1 + x2 * x2;
#pragma unroll
  for (int m = 32; m; m >>= 1) ss += __shfl_xor(ss, m);
  const float inv = rsqrtf(ss * (1.0f / 128.0f) + 1e-6f);
  const float xn1 = x1 * inv * gw[lane], xn2 = x2 * inv * gw[64 + lane];
  const float cs = cache[s * 128 + lane], sn = cache[s * 128 + 64 + lane];
  bf16* o = kf + ((size_t)(b * 8 + hkv) * 2560 + key_off + s) * 128;
  const int dsw = lane ^ ((s & 7) << 3);
  o[dsw]      = (bf16)(xn1 * cs - xn2 * sn);
  o[64 + dsw] = (bf16)(xn2 * cs + xn1 * sn);
}

__global__ __launch_bounds__(256) void transpose_v(const bf16* __restrict__ src, int stride, int base,
                                                   bf16* __restrict__ vtp,
                                                   int S, int key_off) {
  __shared__ bf16 t[32][33];
  const int tid = threadIdx.x;
  const int bh = blockIdx.z;
  const int b = bh >> 3, hkv = bh & 7;
  const int s0 = blockIdx.x * 32, d0 = blockIdx.y * 32;
  const int r = tid >> 3, c4 = (tid & 7) * 4;
  bf16x4 v = *(const bf16x4*)(src + (size_t)(b * S + s0 + r) * stride + base + hkv * 128 + d0 + c4);
  t[r][c4 + 0] = v[0]; t[r][c4 + 1] = v[1]; t[r][c4 + 2] = v[2]; t[r][c4 + 3] = v[3];
  __syncthreads();
  bf16x4 o = { t[c4 + 0][r], t[c4 + 1][r], t[c4 + 2][r], t[c4 + 3][r] };
  *(bf16x4*)(vtp + ((size_t)bh * 128 + d0 + r) * 2560 + key_off + s0 + c4) = o;
}

// ---------------------------------------------------------------- attention
// 768 blocks XCD-chunked; 128 q/block, 4 waves x 32 q; KVBLK=64.
// K double-buffered; V single-buffered (LDS 54272 B <= 160K/3 -> 3 blocks/CU ->
// all 768 blocks in ONE scheduling round, 12 waves/CU overlap).
// vfrag still read AFTER QK (short lifetime — R13's 4-qt spill lesson).
// Max-free softmax (RMSNorm bound |s*log2e| <= 16.3, fp32-safe).
__global__ __launch_bounds__(256, 2) void attn_kernel(const bf16* __restrict__ qf,   // [4096][5120]
                                                      const bf16* __restrict__ kfsw, // [16][2560][128] swz
                                                      const bf16* __restrict__ vtp,  // [16][128][2560]
                                                      bf16* __restrict__ attnb) {    // [4096][3072]
  __shared__ bf16 Ks[2][64 * 128];   // 2 x 16KB K tiles (global pre-swizzled, linear copy)
  __shared__ bf16 Vs[128 * 64];      // 16KB V^T tile, single buffer (swizzled at stage)
  __shared__ char Ps[4][1280];       // per-wave P staging, 16 rows x 80B
  const int tid = threadIdx.x;
  const int wid = tid >> 6, lane = tid & 63;
  const int g = lane >> 4, c = lane & 15;
  const int bid0 = blockIdx.x;
  const int bid  = (bid0 & 7) * 96 + (bid0 >> 3);
  const int qb = bid & 15;
  const int h  = (bid >> 4) % 24;
  const int b  = bid / 384;
  const int q0 = qb * 128 + wid * 32;
  const int hkv = h / 3;
  const char* kfB = (const char*)kfsw + (size_t)(b * 8 + hkv) * 2560 * 256;
  const char* vtB = (const char*)vtp  + (size_t)(b * 8 + hkv) * 128 * 5120;

  bf16x8 qfrag[2][4];
#pragma unroll
  for (int qt = 0; qt < 2; ++qt) {
    const size_t qrow = (size_t)(b * 2048 + q0 + qt * 16 + c) * 5120 + h * 128;
#pragma unroll
    for (int kc = 0; kc < 4; ++kc)
      qfrag[qt][kc] = *(const bf16x8*)(qf + qrow + kc * 32 + g * 8);
  }

  f32x4 ot[2][8] = {};
  float lsum[2] = { 0.f, 0.f };

  auto stageK = [&](int key0, int buf) {
    char* ldst = (char*)&Ks[buf][0] + wid * 4096;
    const char* gsrc = kfB + (size_t)(key0 + wid * 16) * 256
                     + (lane >> 4) * 256 + (lane & 15) * 16;
#pragma unroll
    for (int j = 0; j < 4; ++j)
      gload16(gsrc + j * 1024, ldst + j * 1024);
  };
  auto stageV = [&](int key0) {
    char* ldst = (char*)&Vs[0] + wid * 4096;
    const int r8 = lane >> 3, c8 = lane & 7;
    const char* gsrc = vtB + (size_t)(wid * 32 + r8) * 5120 + (size_t)key0 * 2
                     + ((c8 ^ r8) * 16);
#pragma unroll
    for (int j = 0; j < 4; ++j)
      gload16(gsrc + (size_t)j * 8 * 5120, ldst + j * 1024);
  };

  stageK(0, 0);
  stageV(0);

  for (int it = 0; it < 40; ++it) {
    const int cur = it & 1;
    // barrier A: staged K(this iter) + V(this iter) landed; all waves past prior compute
    asm volatile("s_waitcnt vmcnt(0)" ::: "memory");
    __builtin_amdgcn_s_barrier();
    if (it + 1 < 40) stageK((it + 1) * 64, cur ^ 1);   // other K buffer: no hazard

    const char* Kb = (const char*)&Ks[cur][0];
    const char* Vb = (const char*)&Vs[0];

#pragma unroll
    for (int kb = 0; kb < 2; ++kb) {
      // QK^T (swapped): lane holds S[key_local = kb*32 + 4g+r (|+16)][q=c]
      f32x4 s[2][2] = {};
      __builtin_amdgcn_s_setprio(1);
#pragma unroll
      for (int kc = 0; kc < 4; ++kc) {
        const int bsw = (kc * 64 + g * 16) ^ ((c & 7) << 4);
        bf16x8 a0 = *(const bf16x8*)(Kb + (kb * 32 + c) * 256 + bsw);
        bf16x8 a1 = *(const bf16x8*)(Kb + (kb * 32 + 16 + c) * 256 + bsw);
#pragma unroll
        for (int qt = 0; qt < 2; ++qt) {
          s[qt][0] = __builtin_amdgcn_mfma_f32_16x16x32_bf16(a0, qfrag[qt][kc], s[qt][0], 0, 0, 0);
          s[qt][1] = __builtin_amdgcn_mfma_f32_16x16x32_bf16(a1, qfrag[qt][kc], s[qt][1], 0, 0, 0);
        }
      }
      __builtin_amdgcn_s_setprio(0);

      // V fragments for this key half (short lifetime: read -> PV)
      bf16x8 vfrag[8];
#pragma unroll
      for (int dt = 0; dt < 8; ++dt)
        vfrag[dt] = *(const bf16x8*)(Vb + (dt * 16 + c) * 128 + (((kb * 4 + g) ^ (c & 7)) * 16));
      if (kb == 1) {
        // barrier B: every wave's Vs reads complete -> safe to overwrite Vs with next tile
        asm volatile("s_waitcnt lgkmcnt(0)" ::: "memory");
        __builtin_amdgcn_sched_barrier(0);
        __builtin_amdgcn_s_barrier();
        if (it + 1 < 40) stageV((it + 1) * 64);
      }

#pragma unroll
      for (int qt = 0; qt < 2; ++qt) {
        // max-free softmax: P = exp2(s) directly (bounded by 2^16.3, fp32-safe)
        float p0[4], p1[4];
#pragma unroll
        for (int r = 0; r < 4; ++r) {
          p0[r] = fexp2(s[qt][0][r]);
          p1[r] = fexp2(s[qt][1][r]);
          lsum[qt] += p0[r] + p1[r];
        }
        // P redistribution via per-wave LDS tile: row q=c (80B stride)
        uint2 w0, w1;
        w0.x = pack2bf(p0[0], p0[1]); w0.y = pack2bf(p0[2], p0[3]);
        w1.x = pack2bf(p1[0], p1[1]); w1.y = pack2bf(p1[2], p1[3]);
        *(uint2*)(&Ps[wid][0] + c * 80 + 8 * g)      = w0;   // keys 4g..4g+3
        *(uint2*)(&Ps[wid][0] + c * 80 + 32 + 8 * g) = w1;   // keys 16+4g..
        bf16x8 pf = *(const bf16x8*)(&Ps[wid][0] + c * 80 + g * 16);  // keys 8g..8g+7
        __builtin_amdgcn_s_setprio(1);
#pragma unroll
        for (int dt = 0; dt < 8; ++dt)
          ot[qt][dt] = __builtin_amdgcn_mfma_f32_16x16x32_bf16(vfrag[dt], pf, ot[qt][dt], 0, 0, 0);
        __builtin_amdgcn_s_setprio(0);
      }
    }
  }
  __syncthreads();   // all compute done before osm aliases Ks

  // O^T[d][q] -> per-wave 8KB LDS tile (aliases Ks, dead now; swizzled) -> coalesced global
  char* osm = (char*)&Ks[0][0] + wid * 8192;
#pragma unroll
  for (int qt = 0; qt < 2; ++qt) {
    float ls = lsum[qt];
    ls += __shfl_xor(ls, 16);
    ls += __shfl_xor(ls, 32);
    const float inv = 1.0f / ls;
    const int q = qt * 16 + c;
#pragma unroll
    for (int dt = 0; dt < 8; ++dt) {
      uint2 w2;
      w2.x = pack2bf(ot[qt][dt][0] * inv, ot[qt][dt][1] * inv);
      w2.y = pack2bf(ot[qt][dt][2] * inv, ot[qt][dt][3] * inv);
      *(uint2*)(osm + q * 256 + ((dt * 32 + 8 * g) ^ ((q & 7) << 4))) = w2;
    }
  }
  __syncthreads();
#pragma unroll
  for (int it = 0; it < 8; ++it) {
    const int off = it * 1024 + lane * 16;
    const int qrow = off >> 8, colb = off & 255;
    bf16x8 v = *(const bf16x8*)(osm + qrow * 256 + (colb ^ ((qrow & 7) << 4)));
    *(bf16x8*)((char*)attnb + ((size_t)(b * 2048 + q0 + qrow) * 3072 + h * 128) * 2 + colb) = v;
  }
}

// ---------------------------------------------------------------- launcher
extern "C" void kernel_launch(void* const* d_in, const int* in_sizes, int n_in,
                              void* d_out, int out_size, void* d_ws, size_t ws_size,
                              hipStream_t stream) {
  const float* hs     = (const float*)d_in[0];
  const float* ehs    = (const float*)d_in[1];
  const float* Wq     = (const float*)d_in[2];
  const float* Wk     = (const float*)d_in[3];
  const float* Wv     = (const float*)d_in[4];
  const float* Wak    = (const float*)d_in[5];
  const float* Wav    = (const float*)d_in[6];
  const float* Wo     = (const float*)d_in[7];
  const float* gq     = (const float*)d_in[8];
  const float* gk     = (const float*)d_in[9];
  const float* gak    = (const float*)d_in[10];
  const float* icache = (const float*)d_in[11];
  const float* tcache = (const float*)d_in[12];

  char* ws = (char*)d_ws;
  bf16* hsb    = (bf16*)(ws + 0);            // 25.2MB; reused as attnb after QKV GEMM
  bf16* Wcomb  = (bf16*)(ws + 25165824);     // [5120][3072] 31.5MB (Wq|Wk|Wv)^T; reused for Wot
  bf16* ehsb   = (bf16*)(ws + 56623104);     // 6.3MB; (ehsb+Wacomb region reused as vt)
  bf16* Wacomb = (bf16*)(ws + 62914560);     // [2048][3072] 12.6MB (Wak|Wav)^T
  bf16* qkvC   = (bf16*)(ws + 75497472);     // [4096][5120] 41.9MB (q|k|v)
  bf16* tC     = (bf16*)(ws + 117440512);    // [1024][2048] 4.2MB (tk|tv)
  bf16* kf     = (bf16*)(ws + 121634816);    // 10.5MB joint K [16][2560][128] (swizzled)
  bf16* Wot    = (bf16*)(ws + 25165824);     // 18.9MB, aliases Wcomb (dead after QKV GEMM)
  bf16* vt     = (bf16*)(ws + 56623104);     // 10.5MB joint V^T, aliases ehsb+Wacomb (dead after tGEMM)
  bf16* attnb  = hsb;                        // aliases hsb (dead after QKV GEMM)

  cvt_bf16<<<6144, 256, 0, stream>>>(hs, hsb, 1572864);
  cvt_bf16<<<1536, 256, 0, stream>>>(ehs, ehsb, 393216);
  tcvt<<<dim3(96, 96), 256, 0, stream>>>(Wq,  Wcomb,                3072, 3072);
  tcvt<<<dim3(32, 96), 256, 0, stream>>>(Wk,  Wcomb + 3072 * 3072,  3072, 1024);
  tcvt<<<dim3(32, 96), 256, 0, stream>>>(Wv,  Wcomb + 4096 * 3072,  3072, 1024);
  tcvt<<<dim3(32, 96), 256, 0, stream>>>(Wak, Wacomb,               3072, 1024);
  tcvt<<<dim3(32, 96), 256, 0, stream>>>(Wav, Wacomb + 1024 * 3072, 3072, 1024);

  // fused QKV GEMM (8-phase, 3-slot, 2D XCD tile): [4096][3072] x [5120][3072]^T -> [4096][5120]
  gemm8<bf16><<<640, 512, 0, stream>>>(hsb, Wcomb, qkvC, 5120, 3072, 20);
  // fused tK/tV GEMM (small): [1024][3072] x [2048][3072]^T -> [1024][2048]
  gemm_bt<bf16><<<dim3(16, 8), 256, 0, stream>>>(ehsb, Wacomb, tC, 2048, 3072);

  // Wo transpose-convert AFTER QKV GEMM (reuses Wcomb region)
  tcvt<<<dim3(96, 96), 256, 0, stream>>>(Wo, Wot, 3072, 3072);

  nrope_q<<<24576, 256, 0, stream>>>(qkvC, 5120, gq, icache);
  nrope_k<<<8192, 256, 0, stream>>>(qkvC, 5120, 3072, kf, gk,  icache, 2048, 0);
  nrope_k<<<2048, 256, 0, stream>>>(tC,   2048, 0,    kf, gak, tcache, 512,  2048);
  transpose_v<<<dim3(64, 4, 16), 256, 0, stream>>>(qkvC, 5120, 4096, vt, 2048, 0);
  transpose_v<<<dim3(16, 4, 16), 256, 0, stream>>>(tC,   2048, 1024, vt, 512,  2048);

  attn_kernel<<<768, 256, 0, stream>>>(qkvC, kf, vt, attnb);

  // out-proj GEMM (8-phase, 3-slot, 2D XCD tile): [4096][3072] x [3072][3072]^T -> fp32 d_out
  gemm8<float><<<384, 512, 0, stream>>>(attnb, Wot, (float*)d_out, 3072, 3072, 12);
}

// Round 16
// 545.883 us; speedup vs baseline: 2.1103x; 1.0168x over previous
//
#include <hip/hip_runtime.h>
#include <hip/hip_bf16.h>
#include <math.h>

typedef __bf16 bf16;
typedef __bf16 bf16x4 __attribute__((ext_vector_type(4)));
typedef __bf16 bf16x8 __attribute__((ext_vector_type(8)));
typedef float  f32x4  __attribute__((ext_vector_type(4)));

typedef __attribute__((address_space(1))) void gvoid_t;
typedef __attribute__((address_space(3))) void lvoid_t;

static __device__ __forceinline__ void gload16(const void* g, void* l) {
  // async global->LDS, 16B per lane; LDS dest wave-uniform base (HW adds lane*16)
  __builtin_amdgcn_global_load_lds((gvoid_t*)g, (lvoid_t*)l, 16, 0, 0);
}

static __device__ __forceinline__ float fexp2(float x) {
  return __builtin_amdgcn_exp2f(x);   // v_exp_f32: 2^x
}

static __device__ __forceinline__ unsigned pack2bf(float lo, float hi) {
  unsigned short l = __builtin_bit_cast(unsigned short, (bf16)lo);
  unsigned short h = __builtin_bit_cast(unsigned short, (bf16)hi);
  return ((unsigned)h << 16) | (unsigned)l;
}

// ---------------------------------------------------------------- converts
__global__ __launch_bounds__(256) void cvt_bf16(const float* __restrict__ in,
                                                bf16* __restrict__ out, int n8) {
  int i = blockIdx.x * 256 + threadIdx.x;
  if (i >= n8) return;
  const float4* p = (const float4*)(in + (size_t)i * 8);
  float4 v0 = p[0], v1 = p[1];
  bf16x8 o;
  o[0] = (bf16)v0.x; o[1] = (bf16)v0.y; o[2] = (bf16)v0.z; o[3] = (bf16)v0.w;
  o[4] = (bf16)v1.x; o[5] = (bf16)v1.y; o[6] = (bf16)v1.z; o[7] = (bf16)v1.w;
  *(bf16x8*)(out + (size_t)i * 8) = o;
}

// W [K][N] fp32 -> Wt [N][K] bf16 (32x32 LDS tiles)
__global__ __launch_bounds__(256) void tcvt(const float* __restrict__ W,
                                            bf16* __restrict__ Wt, int K, int N) {
  __shared__ float t[32][33];
  const int tid = threadIdx.x;
  const int r = tid >> 3, c4 = (tid & 7) * 4;
  const size_t grow = (size_t)(blockIdx.y * 32 + r);
  float4 v = *(const float4*)(W + grow * N + blockIdx.x * 32 + c4);
  t[r][c4 + 0] = v.x; t[r][c4 + 1] = v.y; t[r][c4 + 2] = v.z; t[r][c4 + 3] = v.w;
  __syncthreads();
  bf16x4 o = { (bf16)t[c4 + 0][r], (bf16)t[c4 + 1][r], (bf16)t[c4 + 2][r], (bf16)t[c4 + 3][r] };
  *(bf16x4*)(Wt + (size_t)(blockIdx.x * 32 + r) * K + blockIdx.y * 32 + c4) = o;
}

// ---------------------------------------------------------------- GEMM (NT, small shapes)
template <typename OutT>
__global__ __launch_bounds__(256) void gemm_bt(const bf16* __restrict__ A,
                                               const bf16* __restrict__ Bt,
                                               OutT* __restrict__ C,
                                               int N, int K) {
  __shared__ bf16 As[128 * 64];
  __shared__ bf16 Bs[128 * 64];
  const int tid = threadIdx.x;
  const int wid = tid >> 6, lane = tid & 63;
  const int g = lane >> 4, c = lane & 15;
  const int brow = blockIdx.y * 128, bcol = blockIdx.x * 128;
  const int wr = (wid >> 1) * 64, wc = (wid & 1) * 64;
  f32x4 acc[4][4] = {};

  for (int k0 = 0; k0 < K; k0 += 64) {
#pragma unroll
    for (int i = 0; i < 4; ++i) {
      const int off = i * 4096 + tid * 16;
      const int row = off >> 7, colb = off & 127;
      gload16((const char*)A + ((size_t)(brow + row) * K + k0) * 2 + colb,
              (char*)As + i * 4096 + wid * 1024);
      gload16((const char*)Bt + ((size_t)(bcol + row) * K + k0) * 2 + colb,
              (char*)Bs + i * 4096 + wid * 1024);
    }
    __syncthreads();
#pragma unroll
    for (int ks = 0; ks < 2; ++ks) {
      bf16x8 af[4], bfr[4];
#pragma unroll
      for (int t = 0; t < 4; ++t) {
        af[t]  = *(const bf16x8*)(As + (wr + t * 16 + c) * 64 + ks * 32 + g * 8);
        bfr[t] = *(const bf16x8*)(Bs + (wc + t * 16 + c) * 64 + ks * 32 + g * 8);
      }
#pragma unroll
      for (int mt = 0; mt < 4; ++mt)
#pragma unroll
        for (int nt = 0; nt < 4; ++nt)
          acc[mt][nt] = __builtin_amdgcn_mfma_f32_16x16x32_bf16(af[mt], bfr[nt], acc[mt][nt], 0, 0, 0);
    }
    __syncthreads();
  }
#pragma unroll
  for (int mt = 0; mt < 4; ++mt)
#pragma unroll
    for (int nt = 0; nt < 4; ++nt)
#pragma unroll
      for (int r = 0; r < 4; ++r) {
        const int row = brow + wr + mt * 16 + 4 * g + r;
        const int col = bcol + wc + nt * 16 + c;
        C[(size_t)row * N + col] = (OutT)acc[mt][nt][r];
      }
}

// ---------------------------------------------------------------- GEMM (NT, 8-phase, 3-slot)
// BM=128 x BN=256, K-half(32) staging units, 3-slot rotation, counted vmcnt(3).
// 72KB LDS -> 2 blocks/CU co-resident. 2D XCD tile: 16by x (NBX/4)bx per XCD.
template <typename OutT>
__global__ __launch_bounds__(512, 4) void gemm8(const bf16* __restrict__ A,
                                                const bf16* __restrict__ Bt,
                                                OutT* __restrict__ C,
                                                int N, int K, int NBX) {
  __shared__ char As[3 * 8192];
  __shared__ char Bs[3 * 16384];
  const int tid = threadIdx.x;
  const int lane = tid & 63, wid = tid >> 6;
  const int g = lane >> 4, c = lane & 15;
  const int wm = wid >> 2, wn = wid & 3;
  const int xcd = (int)blockIdx.x & 7;
  const int local = (int)blockIdx.x >> 3;
  const int by = (xcd >> 2) * 16 + (local & 15);
  const int bx = (xcd & 3) * (NBX >> 2) + (local >> 4);
  const int brow = by * 128, bcol = bx * 256;
  const int KH = K >> 5;

  f32x4 acc[4][4] = {};

  int LA = wid * 1024 + lane * 16;
  int lnA = LA >> 7;
  int sA = ((LA >> 4) & 7) ^ (lnA & 7);
  const char* Abase = (const char*)(A + (size_t)(brow + lnA * 2 + (sA >> 2)) * K + (sA & 3) * 8);
  int LB0 = wid * 1024 + lane * 16;
  int ln0 = LB0 >> 7;
  int s0 = ((LB0 >> 4) & 7) ^ (ln0 & 7);
  const char* Bbase0 = (const char*)(Bt + (size_t)(bcol + ln0 * 2 + (s0 >> 2)) * K + (s0 & 3) * 8);
  int LB1 = 8192 + wid * 1024 + lane * 16;
  int ln1 = LB1 >> 7;
  int s1 = ((LB1 >> 4) & 7) ^ (ln1 & 7);
  const char* Bbase1 = (const char*)(Bt + (size_t)(bcol + ln1 * 2 + (s1 >> 2)) * K + (s1 & 3) * 8);

  auto stage = [&](int kh, int slot) {
    const size_t koff = (size_t)kh * 64;
    gload16(Abase + koff, As + slot * 8192 + wid * 1024);
    gload16(Bbase0 + koff, Bs + slot * 16384 + wid * 1024);
    gload16(Bbase1 + koff, Bs + slot * 16384 + 8192 + wid * 1024);
  };

  int offA[4], offB[4];
#pragma unroll
  for (int mf = 0; mf < 4; ++mf) {
    const int row = wm * 64 + mf * 16 + c;
    const int ln = row >> 1;
    const int s = (((row & 1) << 2) | g) ^ (ln & 7);
    offA[mf] = ln * 128 + s * 16;
  }
#pragma unroll
  for (int nf = 0; nf < 4; ++nf) {
    const int row = wn * 64 + nf * 16 + c;
    const int ln = row >> 1;
    const int s = (((row & 1) << 2) | g) ^ (ln & 7);
    offB[nf] = ln * 128 + s * 16;
  }

#define GEMM8_PHASE(PHI, KHS)                                                     \
  {                                                                               \
    bf16x8 af[4], bfr[4];                                                         \
    _Pragma("unroll") for (int mf = 0; mf < 4; ++mf)                              \
      af[mf] = *(const bf16x8*)(As + (PHI) * 8192 + offA[mf]);                    \
    _Pragma("unroll") for (int nf = 0; nf < 4; ++nf)                              \
      bfr[nf] = *(const bf16x8*)(Bs + (PHI) * 16384 + offB[nf]);                  \
    stage((KHS), ((PHI) + 2) % 3);                                                \
    asm volatile("s_waitcnt vmcnt(3)" ::: "memory");                              \
    __builtin_amdgcn_s_barrier();                                                 \
    asm volatile("s_waitcnt lgkmcnt(0)" ::: "memory");                            \
    __builtin_amdgcn_sched_barrier(0);                                            \
    __builtin_amdgcn_s_setprio(1);                                                \
    _Pragma("unroll") for (int mf = 0; mf < 4; ++mf)                              \
      _Pragma("unroll") for (int nf = 0; nf < 4; ++nf)                            \
        acc[mf][nf] = __builtin_amdgcn_mfma_f32_16x16x32_bf16(af[mf], bfr[nf],    \
                                                              acc[mf][nf], 0, 0, 0); \
    __builtin_amdgcn_s_setprio(0);                                                \
    __builtin_amdgcn_s_barrier();                                                 \
  }

  stage(0, 0); stage(1, 1);
  asm volatile("s_waitcnt vmcnt(3)" ::: "memory");
  __builtin_amdgcn_s_barrier();

  const int NIT = KH / 3;
  for (int it = 0; it < NIT; ++it) {
    const int kb = it * 3;
    const int kmax = KH - 1;
    GEMM8_PHASE(0, (kb + 2 < kmax ? kb + 2 : kmax));
    GEMM8_PHASE(1, (kb + 3 < kmax ? kb + 3 : kmax));
    GEMM8_PHASE(2, (kb + 4 < kmax ? kb + 4 : kmax));
  }
#undef GEMM8_PHASE

  const int wr = wm * 64, wc = wn * 64;
#pragma unroll
  for (int mf = 0; mf < 4; ++mf)
#pragma unroll
    for (int nf = 0; nf < 4; ++nf)
#pragma unroll
      for (int r = 0; r < 4; ++r) {
        const int row = brow + wr + mf * 16 + 4 * g + r;
        const int col = bcol + wc + nf * 16 + c;
        C[(size_t)row * N + col] = (OutT)acc[mf][nf][r];
      }
}

// ------------------------------------------- RMSNorm + RoPE epilogues
__global__ __launch_bounds__(256) void nrope_q(bf16* __restrict__ q, int stride,
                                               const float* __restrict__ gw,
                                               const float* __restrict__ cache) {
  const float SC = 0.08838834764831845f * 1.4426950408889634f;
  const int w = blockIdx.x * 4 + (threadIdx.x >> 6);
  const int lane = threadIdx.x & 63;
  const int row = w / 24, head = w % 24;
  const int pos = row & 2047;
  bf16* p = q + (size_t)row * stride + head * 128;
  float x1 = (float)p[lane], x2 = (float)p[64 + lane];
  float ss = x1 * x1 + x2 * x2;
#pragma unroll
  for (int m = 32; m; m >>= 1) ss += __shfl_xor(ss, m);
  const float inv = rsqrtf(ss * (1.0f / 128.0f) + 1e-6f);
  const float xn1 = x1 * inv * gw[lane], xn2 = x2 * inv * gw[64 + lane];
  const float cs = cache[pos * 128 + lane] * SC, sn = cache[pos * 128 + 64 + lane] * SC;
  p[lane]      = (bf16)(xn1 * cs - xn2 * sn);
  p[64 + lane] = (bf16)(xn2 * cs + xn1 * sn);
}

__global__ __launch_bounds__(256) void nrope_k(const bf16* __restrict__ src, int stride, int base,
                                               bf16* __restrict__ kf,
                                               const float* __restrict__ gw,
                                               const float* __restrict__ cache,
                                               int S, int key_off) {
  const int w = blockIdx.x * 4 + (threadIdx.x >> 6);
  const int lane = threadIdx.x & 63;
  const int row = w >> 3, hkv = w & 7;
  const int b = row / S, s = row % S;
  const bf16* p = src + (size_t)row * stride + base + hkv * 128;
  float x1 = (float)p[lane], x2 = (float)p[64 + lane];
  float ss = x1 * x1 + x2 * x2;
#pragma unroll
  for (int m = 32; m; m >>= 1) ss += __shfl_xor(ss, m);
  const float inv = rsqrtf(ss * (1.0f / 128.0f) + 1e-6f);
  const float xn1 = x1 * inv * gw[lane], xn2 = x2 * inv * gw[64 + lane];
  const float cs = cache[s * 128 + lane], sn = cache[s * 128 + 64 + lane];
  bf16* o = kf + ((size_t)(b * 8 + hkv) * 2560 + key_off + s) * 128;
  const int dsw = lane ^ ((s & 7) << 3);
  o[dsw]      = (bf16)(xn1 * cs - xn2 * sn);
  o[64 + dsw] = (bf16)(xn2 * cs + xn1 * sn);
}

__global__ __launch_bounds__(256) void transpose_v(const bf16* __restrict__ src, int stride, int base,
                                                   bf16* __restrict__ vtp,
                                                   int S, int key_off) {
  __shared__ bf16 t[32][33];
  const int tid = threadIdx.x;
  const int bh = blockIdx.z;
  const int b = bh >> 3, hkv = bh & 7;
  const int s0 = blockIdx.x * 32, d0 = blockIdx.y * 32;
  const int r = tid >> 3, c4 = (tid & 7) * 4;
  bf16x4 v = *(const bf16x4*)(src + (size_t)(b * S + s0 + r) * stride + base + hkv * 128 + d0 + c4);
  t[r][c4 + 0] = v[0]; t[r][c4 + 1] = v[1]; t[r][c4 + 2] = v[2]; t[r][c4 + 3] = v[3];
  __syncthreads();
  bf16x4 o = { t[c4 + 0][r], t[c4 + 1][r], t[c4 + 2][r], t[c4 + 3][r] };
  *(bf16x4*)(vtp + ((size_t)bh * 128 + d0 + r) * 2560 + key_off + s0 + c4) = o;
}

// ---------------------------------------------------------------- attention
// 768 blocks XCD-chunked; 128 q/block, 4 waves x 32 q; KVBLK=64.
// K AND V single-buffered -> LDS 37.9KB -> 4 blocks/CU, all 768 blocks resident in
// ONE round, 4 waves/SIMD (attn is dependency-latency-bound; TLP is the lever).
// Race ledger: all K/V LDS reads precede barrier B (lgkmcnt0); stages for tile it+1
// issue after B; landing enforced by next iter's barrier A (vmcnt0).
// Max-free softmax (RMSNorm bound |s*log2e| <= 16.3, fp32-safe).
__global__ __launch_bounds__(256, 2) void attn_kernel(const bf16* __restrict__ qf,   // [4096][5120]
                                                      const bf16* __restrict__ kfsw, // [16][2560][128] swz
                                                      const bf16* __restrict__ vtp,  // [16][128][2560]
                                                      bf16* __restrict__ attnb) {    // [4096][3072]
  __shared__ bf16 Ks[64 * 128];      // 16KB K tile, single buffer (pre-swizzled, linear copy)
  __shared__ bf16 Vs[128 * 64];      // 16KB V^T tile, single buffer (swizzled at stage)
  __shared__ char Ps[4][1280];       // per-wave P staging, 16 rows x 80B
  const int tid = threadIdx.x;
  const int wid = tid >> 6, lane = tid & 63;
  const int g = lane >> 4, c = lane & 15;
  const int bid0 = blockIdx.x;
  const int bid  = (bid0 & 7) * 96 + (bid0 >> 3);
  const int qb = bid & 15;
  const int h  = (bid >> 4) % 24;
  const int b  = bid / 384;
  const int q0 = qb * 128 + wid * 32;
  const int hkv = h / 3;
  const char* kfB = (const char*)kfsw + (size_t)(b * 8 + hkv) * 2560 * 256;
  const char* vtB = (const char*)vtp  + (size_t)(b * 8 + hkv) * 128 * 5120;

  bf16x8 qfrag[2][4];
#pragma unroll
  for (int qt = 0; qt < 2; ++qt) {
    const size_t qrow = (size_t)(b * 2048 + q0 + qt * 16 + c) * 5120 + h * 128;
#pragma unroll
    for (int kc = 0; kc < 4; ++kc)
      qfrag[qt][kc] = *(const bf16x8*)(qf + qrow + kc * 32 + g * 8);
  }

  f32x4 ot[2][8] = {};
  float lsum[2] = { 0.f, 0.f };

  auto stageK = [&](int key0) {
    char* ldst = (char*)&Ks[0] + wid * 4096;
    const char* gsrc = kfB + (size_t)(key0 + wid * 16) * 256
                     + (lane >> 4) * 256 + (lane & 15) * 16;
#pragma unroll
    for (int j = 0; j < 4; ++j)
      gload16(gsrc + j * 1024, ldst + j * 1024);
  };
  auto stageV = [&](int key0) {
    char* ldst = (char*)&Vs[0] + wid * 4096;
    const int r8 = lane >> 3, c8 = lane & 7;
    const char* gsrc = vtB + (size_t)(wid * 32 + r8) * 5120 + (size_t)key0 * 2
                     + ((c8 ^ r8) * 16);
#pragma unroll
    for (int j = 0; j < 4; ++j)
      gload16(gsrc + (size_t)j * 8 * 5120, ldst + j * 1024);
  };

  stageK(0);
  stageV(0);

  for (int it = 0; it < 40; ++it) {
    // barrier A: K/V stages landed; all waves past barrier B of previous iter
    asm volatile("s_waitcnt vmcnt(0)" ::: "memory");
    __builtin_amdgcn_s_barrier();

    const char* Kb = (const char*)&Ks[0];
    const char* Vb = (const char*)&Vs[0];

#pragma unroll
    for (int kb = 0; kb < 2; ++kb) {
      // QK^T (swapped): lane holds S[key_local = kb*32 + 4g+r (|+16)][q=c]
      f32x4 s[2][2] = {};
      __builtin_amdgcn_s_setprio(1);
#pragma unroll
      for (int kc = 0; kc < 4; ++kc) {
        const int bsw = (kc * 64 + g * 16) ^ ((c & 7) << 4);
        bf16x8 a0 = *(const bf16x8*)(Kb + (kb * 32 + c) * 256 + bsw);
        bf16x8 a1 = *(const bf16x8*)(Kb + (kb * 32 + 16 + c) * 256 + bsw);
#pragma unroll
        for (int qt = 0; qt < 2; ++qt) {
          s[qt][0] = __builtin_amdgcn_mfma_f32_16x16x32_bf16(a0, qfrag[qt][kc], s[qt][0], 0, 0, 0);
          s[qt][1] = __builtin_amdgcn_mfma_f32_16x16x32_bf16(a1, qfrag[qt][kc], s[qt][1], 0, 0, 0);
        }
      }
      __builtin_amdgcn_s_setprio(0);

      // V fragments for this key half (short lifetime: read -> PV)
      bf16x8 vfrag[8];
#pragma unroll
      for (int dt = 0; dt < 8; ++dt)
        vfrag[dt] = *(const bf16x8*)(Vb + (dt * 16 + c) * 128 + (((kb * 4 + g) ^ (c & 7)) * 16));
      if (kb == 1) {
        // barrier B: every wave's K+V LDS reads complete -> safe to overwrite both tiles
        asm volatile("s_waitcnt lgkmcnt(0)" ::: "memory");
        __builtin_amdgcn_sched_barrier(0);
        __builtin_amdgcn_s_barrier();
        if (it + 1 < 40) {
          stageK((it + 1) * 64);
          stageV((it + 1) * 64);
        }
      }

#pragma unroll
      for (int qt = 0; qt < 2; ++qt) {
        // max-free softmax: P = exp2(s) directly (bounded by 2^16.3, fp32-safe)
        float p0[4], p1[4];
#pragma unroll
        for (int r = 0; r < 4; ++r) {
          p0[r] = fexp2(s[qt][0][r]);
          p1[r] = fexp2(s[qt][1][r]);
          lsum[qt] += p0[r] + p1[r];
        }
        // P redistribution via per-wave LDS tile: row q=c (80B stride)
        uint2 w0, w1;
        w0.x = pack2bf(p0[0], p0[1]); w0.y = pack2bf(p0[2], p0[3]);
        w1.x = pack2bf(p1[0], p1[1]); w1.y = pack2bf(p1[2], p1[3]);
        *(uint2*)(&Ps[wid][0] + c * 80 + 8 * g)      = w0;   // keys 4g..4g+3
        *(uint2*)(&Ps[wid][0] + c * 80 + 32 + 8 * g) = w1;   // keys 16+4g..
        bf16x8 pf = *(const bf16x8*)(&Ps[wid][0] + c * 80 + g * 16);  // keys 8g..8g+7
        __builtin_amdgcn_s_setprio(1);
#pragma unroll
        for (int dt = 0; dt < 8; ++dt)
          ot[qt][dt] = __builtin_amdgcn_mfma_f32_16x16x32_bf16(vfrag[dt], pf, ot[qt][dt], 0, 0, 0);
        __builtin_amdgcn_s_setprio(0);
      }
    }
  }
  __syncthreads();   // all compute done before osm aliases Ks/Vs

  // O^T[d][q] -> per-wave 8KB LDS tile (aliases Ks+Vs, dead now; swizzled) -> coalesced global
  char* osm = (char*)&Ks[0] + wid * 8192;   // 4 waves x 8KB = Ks(16K)+Vs(16K)
#pragma unroll
  for (int qt = 0; qt < 2; ++qt) {
    float ls = lsum[qt];
    ls += __shfl_xor(ls, 16);
    ls += __shfl_xor(ls, 32);
    const float inv = 1.0f / ls;
    const int q = qt * 16 + c;
#pragma unroll
    for (int dt = 0; dt < 8; ++dt) {
      uint2 w2;
      w2.x = pack2bf(ot[qt][dt][0] * inv, ot[qt][dt][1] * inv);
      w2.y = pack2bf(ot[qt][dt][2] * inv, ot[qt][dt][3] * inv);
      *(uint2*)(osm + q * 256 + ((dt * 32 + 8 * g) ^ ((q & 7) << 4))) = w2;
    }
  }
  __syncthreads();
#pragma unroll
  for (int it = 0; it < 8; ++it) {
    const int off = it * 1024 + lane * 16;
    const int qrow = off >> 8, colb = off & 255;
    bf16x8 v = *(const bf16x8*)(osm + qrow * 256 + (colb ^ ((qrow & 7) << 4)));
    *(bf16x8*)((char*)attnb + ((size_t)(b * 2048 + q0 + qrow) * 3072 + h * 128) * 2 + colb) = v;
  }
}

// ---------------------------------------------------------------- launcher
extern "C" void kernel_launch(void* const* d_in, const int* in_sizes, int n_in,
                              void* d_out, int out_size, void* d_ws, size_t ws_size,
                              hipStream_t stream) {
  const float* hs     = (const float*)d_in[0];
  const float* ehs    = (const float*)d_in[1];
  const float* Wq     = (const float*)d_in[2];
  const float* Wk     = (const float*)d_in[3];
  const float* Wv     = (const float*)d_in[4];
  const float* Wak    = (const float*)d_in[5];
  const float* Wav    = (const float*)d_in[6];
  const float* Wo     = (const float*)d_in[7];
  const float* gq     = (const float*)d_in[8];
  const float* gk     = (const float*)d_in[9];
  const float* gak    = (const float*)d_in[10];
  const float* icache = (const float*)d_in[11];
  const float* tcache = (const float*)d_in[12];

  char* ws = (char*)d_ws;
  bf16* hsb    = (bf16*)(ws + 0);            // 25.2MB; reused as attnb after QKV GEMM
  bf16* Wcomb  = (bf16*)(ws + 25165824);     // [5120][3072] 31.5MB (Wq|Wk|Wv)^T; reused for Wot
  bf16* ehsb   = (bf16*)(ws + 56623104);     // 6.3MB; (ehsb+Wacomb region reused as vt)
  bf16* Wacomb = (bf16*)(ws + 62914560);     // [2048][3072] 12.6MB (Wak|Wav)^T
  bf16* qkvC   = (bf16*)(ws + 75497472);     // [4096][5120] 41.9MB (q|k|v)
  bf16* tC     = (bf16*)(ws + 117440512);    // [1024][2048] 4.2MB (tk|tv)
  bf16* kf     = (bf16*)(ws + 121634816);    // 10.5MB joint K [16][2560][128] (swizzled)
  bf16* Wot    = (bf16*)(ws + 25165824);     // 18.9MB, aliases Wcomb (dead after QKV GEMM)
  bf16* vt     = (bf16*)(ws + 56623104);     // 10.5MB joint V^T, aliases ehsb+Wacomb (dead after tGEMM)
  bf16* attnb  = hsb;                        // aliases hsb (dead after QKV GEMM)

  cvt_bf16<<<6144, 256, 0, stream>>>(hs, hsb, 1572864);
  cvt_bf16<<<1536, 256, 0, stream>>>(ehs, ehsb, 393216);
  tcvt<<<dim3(96, 96), 256, 0, stream>>>(Wq,  Wcomb,                3072, 3072);
  tcvt<<<dim3(32, 96), 256, 0, stream>>>(Wk,  Wcomb + 3072 * 3072,  3072, 1024);
  tcvt<<<dim3(32, 96), 256, 0, stream>>>(Wv,  Wcomb + 4096 * 3072,  3072, 1024);
  tcvt<<<dim3(32, 96), 256, 0, stream>>>(Wak, Wacomb,               3072, 1024);
  tcvt<<<dim3(32, 96), 256, 0, stream>>>(Wav, Wacomb + 1024 * 3072, 3072, 1024);

  // fused QKV GEMM (8-phase, 3-slot, 2D XCD tile): [4096][3072] x [5120][3072]^T -> [4096][5120]
  gemm8<bf16><<<640, 512, 0, stream>>>(hsb, Wcomb, qkvC, 5120, 3072, 20);
  // fused tK/tV GEMM (small): [1024][3072] x [2048][3072]^T -> [1024][2048]
  gemm_bt<bf16><<<dim3(16, 8), 256, 0, stream>>>(ehsb, Wacomb, tC, 2048, 3072);

  // Wo transpose-convert AFTER QKV GEMM (reuses Wcomb region)
  tcvt<<<dim3(96, 96), 256, 0, stream>>>(Wo, Wot, 3072, 3072);

  nrope_q<<<24576, 256, 0, stream>>>(qkvC, 5120, gq, icache);
  nrope_k<<<8192, 256, 0, stream>>>(qkvC, 5120, 3072, kf, gk,  icache, 2048, 0);
  nrope_k<<<2048, 256, 0, stream>>>(tC,   2048, 0,    kf, gak, tcache, 512,  2048);
  transpose_v<<<dim3(64, 4, 16), 256, 0, stream>>>(qkvC, 5120, 4096, vt, 2048, 0);
  transpose_v<<<dim3(16, 4, 16), 256, 0, stream>>>(tC,   2048, 1024, vt, 512,  2048);

  attn_kernel<<<768, 256, 0, stream>>>(qkvC, kf, vt, attnb);

  // out-proj GEMM (8-phase, 3-slot, 2D XCD tile): [4096][3072] x [3072][3072]^T -> fp32 d_out
  gemm8<float><<<384, 512, 0, stream>>>(attnb, Wot, (float*)d_out, 3072, 3072, 12);
}

// Round 18
// 533.468 us; speedup vs baseline: 2.1594x; 1.0233x over previous
//
#include <hip/hip_runtime.h>
#include <hip/hip_bf16.h>
#include <math.h>

typedef __bf16 bf16;
typedef __bf16 bf16x4 __attribute__((ext_vector_type(4)));
typedef __bf16 bf16x8 __attribute__((ext_vector_type(8)));
typedef float  f32x4  __attribute__((ext_vector_type(4)));

typedef __attribute__((address_space(1))) void gvoid_t;
typedef __attribute__((address_space(3))) void lvoid_t;

static __device__ __forceinline__ void gload16(const void* g, void* l) {
  // async global->LDS, 16B per lane; LDS dest wave-uniform base (HW adds lane*16)
  __builtin_amdgcn_global_load_lds((gvoid_t*)g, (lvoid_t*)l, 16, 0, 0);
}

static __device__ __forceinline__ float fexp2(float x) {
  return __builtin_amdgcn_exp2f(x);   // v_exp_f32: 2^x
}

static __device__ __forceinline__ unsigned pack2bf(float lo, float hi) {
  unsigned short l = __builtin_bit_cast(unsigned short, (bf16)lo);
  unsigned short h = __builtin_bit_cast(unsigned short, (bf16)hi);
  return ((unsigned)h << 16) | (unsigned)l;
}

// ---------------------------------------------------------------- converts
__global__ __launch_bounds__(256) void cvt_bf16(const float* __restrict__ in,
                                                bf16* __restrict__ out, int n8) {
  int i = blockIdx.x * 256 + threadIdx.x;
  if (i >= n8) return;
  const float4* p = (const float4*)(in + (size_t)i * 8);
  float4 v0 = p[0], v1 = p[1];
  bf16x8 o;
  o[0] = (bf16)v0.x; o[1] = (bf16)v0.y; o[2] = (bf16)v0.z; o[3] = (bf16)v0.w;
  o[4] = (bf16)v1.x; o[5] = (bf16)v1.y; o[6] = (bf16)v1.z; o[7] = (bf16)v1.w;
  *(bf16x8*)(out + (size_t)i * 8) = o;
}

// W [K][N] fp32 -> Wt [N][K] bf16 (32x32 LDS tiles)
__global__ __launch_bounds__(256) void tcvt(const float* __restrict__ W,
                                            bf16* __restrict__ Wt, int K, int N) {
  __shared__ float t[32][33];
  const int tid = threadIdx.x;
  const int r = tid >> 3, c4 = (tid & 7) * 4;
  const size_t grow = (size_t)(blockIdx.y * 32 + r);
  float4 v = *(const float4*)(W + grow * N + blockIdx.x * 32 + c4);
  t[r][c4 + 0] = v.x; t[r][c4 + 1] = v.y; t[r][c4 + 2] = v.z; t[r][c4 + 3] = v.w;
  __syncthreads();
  bf16x4 o = { (bf16)t[c4 + 0][r], (bf16)t[c4 + 1][r], (bf16)t[c4 + 2][r], (bf16)t[c4 + 3][r] };
  *(bf16x4*)(Wt + (size_t)(blockIdx.x * 32 + r) * K + blockIdx.y * 32 + c4) = o;
}

// ---------------------------------------------------------------- GEMM (NT, 8-phase, 3-slot)
// BM=128 x BN=256, K-half(32) staging units, 3-slot rotation.
// Phase order v2 (2-phase stage slack): {vmcnt(3); barrier; ds_read slot p;
// stage unit p+2 -> slot (p+2)%3; lgkmcnt(0); MFMA x16; barrier}.
// Ledger: cross-wave RAW — each wave's vmcnt(3) then barrier => all waves' unit-p
// loads landed before any wave's slot-p reads. WAR on slot (p+2)%3: last read one
// phase earlier, separated by that phase's end barrier.
// 72KB LDS -> 2 blocks/CU. 2D XCD tile: (NBY/2) x (NBX/4) chunk per XCD.
// REQUIRES: grid == NBY*NBX, NBY%2==0, NBX%4==0, NBX == N/256, NBY == M/128.
template <typename OutT>
__global__ __launch_bounds__(512, 4) void gemm8(const bf16* __restrict__ A,
                                                const bf16* __restrict__ Bt,
                                                OutT* __restrict__ C,
                                                int N, int K, int NBX, int NBY) {
  __shared__ char As[3 * 8192];
  __shared__ char Bs[3 * 16384];
  const int tid = threadIdx.x;
  const int lane = tid & 63, wid = tid >> 6;
  const int g = lane >> 4, c = lane & 15;
  const int wm = wid >> 2, wn = wid & 3;
  const int xcd = (int)blockIdx.x & 7;
  const int local = (int)blockIdx.x >> 3;
  const int hy = NBY >> 1, qx = NBX >> 2;
  const int by = (xcd >> 2) * hy + (local % hy);
  const int bx = (xcd & 3) * qx + (local / hy);
  const int brow = by * 128, bcol = bx * 256;
  const int KH = K >> 5;

  f32x4 acc[4][4] = {};

  int LA = wid * 1024 + lane * 16;
  int lnA = LA >> 7;
  int sA = ((LA >> 4) & 7) ^ (lnA & 7);
  const char* Abase = (const char*)(A + (size_t)(brow + lnA * 2 + (sA >> 2)) * K + (sA & 3) * 8);
  int LB0 = wid * 1024 + lane * 16;
  int ln0 = LB0 >> 7;
  int s0 = ((LB0 >> 4) & 7) ^ (ln0 & 7);
  const char* Bbase0 = (const char*)(Bt + (size_t)(bcol + ln0 * 2 + (s0 >> 2)) * K + (s0 & 3) * 8);
  int LB1 = 8192 + wid * 1024 + lane * 16;
  int ln1 = LB1 >> 7;
  int s1 = ((LB1 >> 4) & 7) ^ (ln1 & 7);
  const char* Bbase1 = (const char*)(Bt + (size_t)(bcol + ln1 * 2 + (s1 >> 2)) * K + (s1 & 3) * 8);

  auto stage = [&](int kh, int slot) {   // 3 x gload16 = one K-half unit (A 8KB + B 16KB)
    const size_t koff = (size_t)kh * 64;
    gload16(Abase + koff, As + slot * 8192 + wid * 1024);
    gload16(Bbase0 + koff, Bs + slot * 16384 + wid * 1024);
    gload16(Bbase1 + koff, Bs + slot * 16384 + 8192 + wid * 1024);
  };

  int offA[4], offB[4];
#pragma unroll
  for (int mf = 0; mf < 4; ++mf) {
    const int row = wm * 64 + mf * 16 + c;
    const int ln = row >> 1;
    const int s = (((row & 1) << 2) | g) ^ (ln & 7);
    offA[mf] = ln * 128 + s * 16;
  }
#pragma unroll
  for (int nf = 0; nf < 4; ++nf) {
    const int row = wn * 64 + nf * 16 + c;
    const int ln = row >> 1;
    const int s = (((row & 1) << 2) | g) ^ (ln & 7);
    offB[nf] = ln * 128 + s * 16;
  }

#define GEMM8_PHASE(PHI, KHS)                                                     \
  {                                                                               \
    asm volatile("s_waitcnt vmcnt(3)" ::: "memory");                              \
    __builtin_amdgcn_s_barrier();                                                 \
    bf16x8 af[4], bfr[4];                                                         \
    _Pragma("unroll") for (int mf = 0; mf < 4; ++mf)                              \
      af[mf] = *(const bf16x8*)(As + (PHI) * 8192 + offA[mf]);                    \
    _Pragma("unroll") for (int nf = 0; nf < 4; ++nf)                              \
      bfr[nf] = *(const bf16x8*)(Bs + (PHI) * 16384 + offB[nf]);                  \
    stage((KHS), ((PHI) + 2) % 3);                                                \
    asm volatile("s_waitcnt lgkmcnt(0)" ::: "memory");                            \
    __builtin_amdgcn_sched_barrier(0);                                            \
    __builtin_amdgcn_s_setprio(1);                                                \
    _Pragma("unroll") for (int mf = 0; mf < 4; ++mf)                              \
      _Pragma("unroll") for (int nf = 0; nf < 4; ++nf)                            \
        acc[mf][nf] = __builtin_amdgcn_mfma_f32_16x16x32_bf16(af[mf], bfr[nf],    \
                                                              acc[mf][nf], 0, 0, 0); \
    __builtin_amdgcn_s_setprio(0);                                                \
    __builtin_amdgcn_s_barrier();                                                 \
  }

  // prologue: units 0,1 in flight (6 loads); phase 0's vmcnt(3) ensures unit 0 landed
  stage(0, 0); stage(1, 1);

  const int NIT = KH / 3;
  for (int it = 0; it < NIT; ++it) {
    const int kb = it * 3;
    const int kmax = KH - 1;
    GEMM8_PHASE(0, (kb + 2 < kmax ? kb + 2 : kmax));
    GEMM8_PHASE(1, (kb + 3 < kmax ? kb + 3 : kmax));
    GEMM8_PHASE(2, (kb + 4 < kmax ? kb + 4 : kmax));
  }
#undef GEMM8_PHASE

  const int wr = wm * 64, wc = wn * 64;
#pragma unroll
  for (int mf = 0; mf < 4; ++mf)
#pragma unroll
    for (int nf = 0; nf < 4; ++nf)
#pragma unroll
      for (int r = 0; r < 4; ++r) {
        const int row = brow + wr + mf * 16 + 4 * g + r;
        const int col = bcol + wc + nf * 16 + c;
        C[(size_t)row * N + col] = (OutT)acc[mf][nf][r];
      }
}

// ------------------------------------------- RMSNorm + RoPE epilogues
__global__ __launch_bounds__(256) void nrope_q(bf16* __restrict__ q, int stride,
                                               const float* __restrict__ gw,
                                               const float* __restrict__ cache) {
  const float SC = 0.08838834764831845f * 1.4426950408889634f;
  const int w = blockIdx.x * 4 + (threadIdx.x >> 6);
  const int lane = threadIdx.x & 63;
  const int row = w / 24, head = w % 24;
  const int pos = row & 2047;
  bf16* p = q + (size_t)row * stride + head * 128;
  float x1 = (float)p[lane], x2 = (float)p[64 + lane];
  float ss = x1 * x1 + x2 * x2;
#pragma unroll
  for (int m = 32; m; m >>= 1) ss += __shfl_xor(ss, m);
  const float inv = rsqrtf(ss * (1.0f / 128.0f) + 1e-6f);
  const float xn1 = x1 * inv * gw[lane], xn2 = x2 * inv * gw[64 + lane];
  const float cs = cache[pos * 128 + lane] * SC, sn = cache[pos * 128 + 64 + lane] * SC;
  p[lane]      = (bf16)(xn1 * cs - xn2 * sn);
  p[64 + lane] = (bf16)(xn2 * cs + xn1 * sn);
}

__global__ __launch_bounds__(256) void nrope_k(const bf16* __restrict__ src, int stride, int base,
                                               bf16* __restrict__ kf,
                                               const float* __restrict__ gw,
                                               const float* __restrict__ cache,
                                               int S, int key_off) {
  const int w = blockIdx.x * 4 + (threadIdx.x >> 6);
  const int lane = threadIdx.x & 63;
  const int row = w >> 3, hkv = w & 7;
  const int b = row / S, s = row % S;
  const bf16* p = src + (size_t)row * stride + base + hkv * 128;
  float x1 = (float)p[lane], x2 = (float)p[64 + lane];
  float ss = x1 * x1 + x2 * x2;
#pragma unroll
  for (int m = 32; m; m >>= 1) ss += __shfl_xor(ss, m);
  const float inv = rsqrtf(ss * (1.0f / 128.0f) + 1e-6f);
  const float xn1 = x1 * inv * gw[lane], xn2 = x2 * inv * gw[64 + lane];
  const float cs = cache[s * 128 + lane], sn = cache[s * 128 + 64 + lane];
  bf16* o = kf + ((size_t)(b * 8 + hkv) * 2560 + key_off + s) * 128;
  const int dsw = lane ^ ((s & 7) << 3);
  o[dsw]      = (bf16)(xn1 * cs - xn2 * sn);
  o[64 + dsw] = (bf16)(xn2 * cs + xn1 * sn);
}

__global__ __launch_bounds__(256) void transpose_v(const bf16* __restrict__ src, int stride, int base,
                                                   bf16* __restrict__ vtp,
                                                   int S, int key_off) {
  __shared__ bf16 t[32][33];
  const int tid = threadIdx.x;
  const int bh = blockIdx.z;
  const int b = bh >> 3, hkv = bh & 7;
  const int s0 = blockIdx.x * 32, d0 = blockIdx.y * 32;
  const int r = tid >> 3, c4 = (tid & 7) * 4;
  bf16x4 v = *(const bf16x4*)(src + (size_t)(b * S + s0 + r) * stride + base + hkv * 128 + d0 + c4);
  t[r][c4 + 0] = v[0]; t[r][c4 + 1] = v[1]; t[r][c4 + 2] = v[2]; t[r][c4 + 3] = v[3];
  __syncthreads();
  bf16x4 o = { t[c4 + 0][r], t[c4 + 1][r], t[c4 + 2][r], t[c4 + 3][r] };
  *(bf16x4*)(vtp + ((size_t)bh * 128 + d0 + r) * 2560 + key_off + s0 + c4) = o;
}

// ---------------------------------------------------------------- attention (R16 known-good)
// 768 blocks XCD-chunked; 128 q/block, 4 waves x 32 q; KVBLK=64; K+V single-buffered
// (LDS 37.9KB); max-free softmax (RMSNorm bound |s*log2e| <= 16.3).
__global__ __launch_bounds__(256, 2) void attn_kernel(const bf16* __restrict__ qf,   // [4096][5120]
                                                      const bf16* __restrict__ kfsw, // [16][2560][128] swz
                                                      const bf16* __restrict__ vtp,  // [16][128][2560]
                                                      bf16* __restrict__ attnb) {    // [4096][3072]
  __shared__ bf16 Ks[64 * 128];
  __shared__ bf16 Vs[128 * 64];
  __shared__ char Ps[4][1280];
  const int tid = threadIdx.x;
  const int wid = tid >> 6, lane = tid & 63;
  const int g = lane >> 4, c = lane & 15;
  const int bid0 = blockIdx.x;
  const int bid  = (bid0 & 7) * 96 + (bid0 >> 3);
  const int qb = bid & 15;
  const int h  = (bid >> 4) % 24;
  const int b  = bid / 384;
  const int q0 = qb * 128 + wid * 32;
  const int hkv = h / 3;
  const char* kfB = (const char*)kfsw + (size_t)(b * 8 + hkv) * 2560 * 256;
  const char* vtB = (const char*)vtp  + (size_t)(b * 8 + hkv) * 128 * 5120;

  bf16x8 qfrag[2][4];
#pragma unroll
  for (int qt = 0; qt < 2; ++qt) {
    const size_t qrow = (size_t)(b * 2048 + q0 + qt * 16 + c) * 5120 + h * 128;
#pragma unroll
    for (int kc = 0; kc < 4; ++kc)
      qfrag[qt][kc] = *(const bf16x8*)(qf + qrow + kc * 32 + g * 8);
  }

  f32x4 ot[2][8] = {};
  float lsum[2] = { 0.f, 0.f };

  auto stageK = [&](int key0) {
    char* ldst = (char*)&Ks[0] + wid * 4096;
    const char* gsrc = kfB + (size_t)(key0 + wid * 16) * 256
                     + (lane >> 4) * 256 + (lane & 15) * 16;
#pragma unroll
    for (int j = 0; j < 4; ++j)
      gload16(gsrc + j * 1024, ldst + j * 1024);
  };
  auto stageV = [&](int key0) {
    char* ldst = (char*)&Vs[0] + wid * 4096;
    const int r8 = lane >> 3, c8 = lane & 7;
    const char* gsrc = vtB + (size_t)(wid * 32 + r8) * 5120 + (size_t)key0 * 2
                     + ((c8 ^ r8) * 16);
#pragma unroll
    for (int j = 0; j < 4; ++j)
      gload16(gsrc + (size_t)j * 8 * 5120, ldst + j * 1024);
  };

  stageK(0);
  stageV(0);

  for (int it = 0; it < 40; ++it) {
    asm volatile("s_waitcnt vmcnt(0)" ::: "memory");
    __builtin_amdgcn_s_barrier();

    const char* Kb = (const char*)&Ks[0];
    const char* Vb = (const char*)&Vs[0];

#pragma unroll
    for (int kb = 0; kb < 2; ++kb) {
      f32x4 s[2][2] = {};
      __builtin_amdgcn_s_setprio(1);
#pragma unroll
      for (int kc = 0; kc < 4; ++kc) {
        const int bsw = (kc * 64 + g * 16) ^ ((c & 7) << 4);
        bf16x8 a0 = *(const bf16x8*)(Kb + (kb * 32 + c) * 256 + bsw);
        bf16x8 a1 = *(const bf16x8*)(Kb + (kb * 32 + 16 + c) * 256 + bsw);
#pragma unroll
        for (int qt = 0; qt < 2; ++qt) {
          s[qt][0] = __builtin_amdgcn_mfma_f32_16x16x32_bf16(a0, qfrag[qt][kc], s[qt][0], 0, 0, 0);
          s[qt][1] = __builtin_amdgcn_mfma_f32_16x16x32_bf16(a1, qfrag[qt][kc], s[qt][1], 0, 0, 0);
        }
      }
      __builtin_amdgcn_s_setprio(0);

      bf16x8 vfrag[8];
#pragma unroll
      for (int dt = 0; dt < 8; ++dt)
        vfrag[dt] = *(const bf16x8*)(Vb + (dt * 16 + c) * 128 + (((kb * 4 + g) ^ (c & 7)) * 16));
      if (kb == 1) {
        asm volatile("s_waitcnt lgkmcnt(0)" ::: "memory");
        __builtin_amdgcn_sched_barrier(0);
        __builtin_amdgcn_s_barrier();
        if (it + 1 < 40) {
          stageK((it + 1) * 64);
          stageV((it + 1) * 64);
        }
      }

#pragma unroll
      for (int qt = 0; qt < 2; ++qt) {
        float p0[4], p1[4];
#pragma unroll
        for (int r = 0; r < 4; ++r) {
          p0[r] = fexp2(s[qt][0][r]);
          p1[r] = fexp2(s[qt][1][r]);
          lsum[qt] += p0[r] + p1[r];
        }
        uint2 w0, w1;
        w0.x = pack2bf(p0[0], p0[1]); w0.y = pack2bf(p0[2], p0[3]);
        w1.x = pack2bf(p1[0], p1[1]); w1.y = pack2bf(p1[2], p1[3]);
        *(uint2*)(&Ps[wid][0] + c * 80 + 8 * g)      = w0;
        *(uint2*)(&Ps[wid][0] + c * 80 + 32 + 8 * g) = w1;
        bf16x8 pf = *(const bf16x8*)(&Ps[wid][0] + c * 80 + g * 16);
        __builtin_amdgcn_s_setprio(1);
#pragma unroll
        for (int dt = 0; dt < 8; ++dt)
          ot[qt][dt] = __builtin_amdgcn_mfma_f32_16x16x32_bf16(vfrag[dt], pf, ot[qt][dt], 0, 0, 0);
        __builtin_amdgcn_s_setprio(0);
      }
    }
  }
  __syncthreads();

  char* osm = (char*)&Ks[0] + wid * 8192;
#pragma unroll
  for (int qt = 0; qt < 2; ++qt) {
    float ls = lsum[qt];
    ls += __shfl_xor(ls, 16);
    ls += __shfl_xor(ls, 32);
    const float inv = 1.0f / ls;
    const int q = qt * 16 + c;
#pragma unroll
    for (int dt = 0; dt < 8; ++dt) {
      uint2 w2;
      w2.x = pack2bf(ot[qt][dt][0] * inv, ot[qt][dt][1] * inv);
      w2.y = pack2bf(ot[qt][dt][2] * inv, ot[qt][dt][3] * inv);
      *(uint2*)(osm + q * 256 + ((dt * 32 + 8 * g) ^ ((q & 7) << 4))) = w2;
    }
  }
  __syncthreads();
#pragma unroll
  for (int it = 0; it < 8; ++it) {
    const int off = it * 1024 + lane * 16;
    const int qrow = off >> 8, colb = off & 255;
    bf16x8 v = *(const bf16x8*)(osm + qrow * 256 + (colb ^ ((qrow & 7) << 4)));
    *(bf16x8*)((char*)attnb + ((size_t)(b * 2048 + q0 + qrow) * 3072 + h * 128) * 2 + colb) = v;
  }
}

// ---------------------------------------------------------------- launcher
extern "C" void kernel_launch(void* const* d_in, const int* in_sizes, int n_in,
                              void* d_out, int out_size, void* d_ws, size_t ws_size,
                              hipStream_t stream) {
  const float* hs     = (const float*)d_in[0];
  const float* ehs    = (const float*)d_in[1];
  const float* Wq     = (const float*)d_in[2];
  const float* Wk     = (const float*)d_in[3];
  const float* Wv     = (const float*)d_in[4];
  const float* Wak    = (const float*)d_in[5];
  const float* Wav    = (const float*)d_in[6];
  const float* Wo     = (const float*)d_in[7];
  const float* gq     = (const float*)d_in[8];
  const float* gk     = (const float*)d_in[9];
  const float* gak    = (const float*)d_in[10];
  const float* icache = (const float*)d_in[11];
  const float* tcache = (const float*)d_in[12];

  char* ws = (char*)d_ws;
  bf16* hsb    = (bf16*)(ws + 0);            // 25.2MB; reused as attnb after QKV GEMM
  bf16* Wcomb  = (bf16*)(ws + 25165824);     // [5120][3072] 31.5MB (Wq|Wk|Wv)^T; reused for Wot
  bf16* ehsb   = (bf16*)(ws + 56623104);     // 6.3MB; (ehsb+Wacomb region reused as vt)
  bf16* Wacomb = (bf16*)(ws + 62914560);     // [2048][3072] 12.6MB (Wak|Wav)^T
  bf16* qkvC   = (bf16*)(ws + 75497472);     // [4096][5120] 41.9MB (q|k|v)
  bf16* tC     = (bf16*)(ws + 117440512);    // [1024][2048] 4.2MB (tk|tv)
  bf16* kf     = (bf16*)(ws + 121634816);    // 10.5MB joint K [16][2560][128] (swizzled)
  bf16* Wot    = (bf16*)(ws + 25165824);     // 18.9MB, aliases Wcomb (dead after QKV GEMM)
  bf16* vt     = (bf16*)(ws + 56623104);     // 10.5MB joint V^T, aliases ehsb+Wacomb (dead after tGEMM)
  bf16* attnb  = hsb;                        // aliases hsb (dead after QKV GEMM)

  cvt_bf16<<<6144, 256, 0, stream>>>(hs, hsb, 1572864);
  cvt_bf16<<<1536, 256, 0, stream>>>(ehs, ehsb, 393216);
  tcvt<<<dim3(96, 96), 256, 0, stream>>>(Wq,  Wcomb,                3072, 3072);
  tcvt<<<dim3(32, 96), 256, 0, stream>>>(Wk,  Wcomb + 3072 * 3072,  3072, 1024);
  tcvt<<<dim3(32, 96), 256, 0, stream>>>(Wv,  Wcomb + 4096 * 3072,  3072, 1024);
  tcvt<<<dim3(32, 96), 256, 0, stream>>>(Wak, Wacomb,               3072, 1024);
  tcvt<<<dim3(32, 96), 256, 0, stream>>>(Wav, Wacomb + 1024 * 3072, 3072, 1024);

  // fused QKV GEMM: [4096][3072] x [5120][3072]^T -> [4096][5120]  (NBY=32, NBX=20)
  gemm8<bf16><<<640, 512, 0, stream>>>(hsb, Wcomb, qkvC, 5120, 3072, 20, 32);
  // fused tK/tV GEMM: [1024][3072] x [2048][3072]^T -> [1024][2048]  (NBY=8, NBX=8, grid 64)
  gemm8<bf16><<<64, 512, 0, stream>>>(ehsb, Wacomb, tC, 2048, 3072, 8, 8);

  // Wo transpose-convert AFTER QKV GEMM (reuses Wcomb region)
  tcvt<<<dim3(96, 96), 256, 0, stream>>>(Wo, Wot, 3072, 3072);

  nrope_q<<<24576, 256, 0, stream>>>(qkvC, 5120, gq, icache);
  nrope_k<<<8192, 256, 0, stream>>>(qkvC, 5120, 3072, kf, gk,  icache, 2048, 0);
  nrope_k<<<2048, 256, 0, stream>>>(tC,   2048, 0,    kf, gak, tcache, 512,  2048);
  transpose_v<<<dim3(64, 4, 16), 256, 0, stream>>>(qkvC, 5120, 4096, vt, 2048, 0);
  transpose_v<<<dim3(16, 4, 16), 256, 0, stream>>>(tC,   2048, 1024, vt, 512,  2048);

  attn_kernel<<<768, 256, 0, stream>>>(qkvC, kf, vt, attnb);

  // out-proj GEMM: [4096][3072] x [3072][3072]^T -> fp32 d_out  (NBY=32, NBX=12)
  gemm8<float><<<384, 512, 0, stream>>>(attnb, Wot, (float*)d_out, 3072, 3072, 12, 32);
}